// Round 1
// baseline (319.484 us; speedup 1.0000x reference)
//
#include <hip/hip_runtime.h>
#include <hip/hip_bf16.h>

#define Bc 8
#define Sc 2048
#define Hc 8
#define Dc 64
#define Ec 512
#define NTc 64
#define Tc (Bc*Sc)
#define N1c (4*Hc*Dc)
#define HISTc (Sc - NTc)

typedef float f32x4 __attribute__((ext_vector_type(4)));
typedef __bf16 bf16x8 __attribute__((ext_vector_type(8)));
typedef short short8 __attribute__((ext_vector_type(8)));
typedef short s4v __attribute__((ext_vector_type(4)));

__device__ __forceinline__ unsigned short f2bf(float f){
  unsigned int u = __float_as_uint(f);
  u += 0x7fffu + ((u >> 16) & 1u);
  return (unsigned short)(u >> 16);
}
__device__ __forceinline__ float bf2f(unsigned short h){
  return __uint_as_float(((unsigned int)h) << 16);
}
// packed f32x2 -> bf16x2 (v_cvt_pk_bf16_f32)
__device__ __forceinline__ unsigned int pkbf(float a, float b){
  float2 f; f.x = a; f.y = b;
  __hip_bfloat162 h = __float22bfloat162_rn(f);
  unsigned int u;
  __builtin_memcpy(&u, &h, 4);
  return u;
}
__device__ __forceinline__ s4v pk4(float a, float b, float c, float d){
  uint2 u; u.x = pkbf(a, b); u.y = pkbf(c, d);
  return __builtin_bit_cast(s4v, u);
}
__device__ __forceinline__ float silu_f(float x){
  return x * __builtin_amdgcn_rcpf(1.f + __expf(-x));
}
__device__ __forceinline__ bf16x8 ldb8(const unsigned short* p){
  return __builtin_bit_cast(bf16x8, *(const short8*)p);
}
__device__ __forceinline__ f32x4 mfma16(bf16x8 a, bf16x8 b, f32x4 c){
  return __builtin_amdgcn_mfma_f32_16x16x32_bf16(a, b, c, 0, 0, 0);
}
__device__ __forceinline__ void gl_lds16(const void* g, void* l){
  __builtin_amdgcn_global_load_lds((const __attribute__((address_space(1))) unsigned int*)g,
                                   (__attribute__((address_space(3))) unsigned int*)l, 16, 0, 0);
}

// ---------------- transpose + cast fp32 -> bf16 : out[c][r] = in[r][c] ----------------
__global__ __launch_bounds__(1024) void k_transpose_cast(const float* __restrict__ in,
                                                         unsigned short* __restrict__ out,
                                                         int R, int C){
  __shared__ float tile[32][33];
  int tx = threadIdx.x, ty = threadIdx.y;
  int c0 = blockIdx.x * 32, r0 = blockIdx.y * 32;
  tile[ty][tx] = in[(size_t)(r0 + ty) * C + c0 + tx];
  __syncthreads();
  out[(size_t)(c0 + ty) * R + r0 + tx] = f2bf(tile[tx][ty]);
}

// ---------------- input layernorm -> bf16 (one wave per row of 512) ----------------
__global__ __launch_bounds__(256) void k_ln_in(const float* __restrict__ x, const float* __restrict__ g,
                                               const float* __restrict__ b, unsigned short* __restrict__ xn){
  int lane = threadIdx.x & 63;
  int row = blockIdx.x * 4 + (threadIdx.x >> 6);
  const float* xr = x + (size_t)row * Ec + lane * 8;
  float4 v0 = *(const float4*)xr;
  float4 v1 = *(const float4*)(xr + 4);
  float vv[8] = {v0.x, v0.y, v0.z, v0.w, v1.x, v1.y, v1.z, v1.w};
  float s = 0.f, ss = 0.f;
  #pragma unroll
  for (int j = 0; j < 8; ++j){ s += vv[j]; ss += vv[j] * vv[j]; }
  #pragma unroll
  for (int m = 1; m < 64; m <<= 1){ s += __shfl_xor(s, m); ss += __shfl_xor(ss, m); }
  float mu = s * (1.f / Ec);
  float rs = rsqrtf(ss * (1.f / Ec) - mu * mu + 1e-5f);
  int c = lane * 8;
  float o[8];
  #pragma unroll
  for (int j = 0; j < 8; ++j) o[j] = (vv[j] - mu) * rs * g[c + j] + b[c + j];
  uint4 pk; pk.x = pkbf(o[0], o[1]); pk.y = pkbf(o[2], o[3]);
  pk.z = pkbf(o[4], o[5]); pk.w = pkbf(o[6], o[7]);
  *(uint4*)(xn + (size_t)row * Ec + c) = pk;
}

// ---------------- ln(attn_out) * u -> bf16 (att and u are bf16) ----------------
__global__ __launch_bounds__(256) void k_ln_mul(const unsigned short* __restrict__ att, const float* __restrict__ g,
                                                const float* __restrict__ b, const unsigned short* __restrict__ u,
                                                unsigned short* __restrict__ par){
  int lane = threadIdx.x & 63;
  int row = blockIdx.x * 4 + (threadIdx.x >> 6);
  short8 a8 = *(const short8*)(att + (size_t)row * Ec + lane * 8);
  short8 u8 = *(const short8*)(u + (size_t)row * Ec + lane * 8);
  float vv[8];
  #pragma unroll
  for (int j = 0; j < 8; ++j) vv[j] = bf2f((unsigned short)a8[j]);
  float s = 0.f, ss = 0.f;
  #pragma unroll
  for (int j = 0; j < 8; ++j){ s += vv[j]; ss += vv[j] * vv[j]; }
  #pragma unroll
  for (int m = 1; m < 64; m <<= 1){ s += __shfl_xor(s, m); ss += __shfl_xor(ss, m); }
  float mu = s * (1.f / Ec);
  float rs = rsqrtf(ss * (1.f / Ec) - mu * mu + 1e-5f);
  int c = lane * 8;
  float o[8];
  #pragma unroll
  for (int j = 0; j < 8; ++j){
    float uu = bf2f((unsigned short)u8[j]);
    o[j] = uu * ((vv[j] - mu) * rs * g[c + j] + b[c + j]);
  }
  uint4 pk; pk.x = pkbf(o[0], o[1]); pk.y = pkbf(o[2], o[3]);
  pk.z = pkbf(o[4], o[5]); pk.w = pkbf(o[6], o[7]);
  *(uint4*)(par + (size_t)row * Ec + c) = pk;
}

// ======================= GEMM1: 256x256 tile, BK=64, 8 waves, 8-phase =======================
// LDS: 2 dbuf slots x 2 K-step halves x (256 rows x 32 cols bf16 = 16KB) per matrix = 128KB.
// Halves split along K so each half's last read is 1+ phase before its restage (WAR-safe).
// Counted vmcnt(6) at phases 4/8 only: 7 halves in flight, waits leave 3 -> never drains.
// LDS xor-swizzle: chunk ^= (row>>1)&3 realized by pre-swizzling the global source address
// (gl_lds writes linearly). Read bank-sets then spread all 32 banks per quarter-wave.

__device__ __forceinline__ void lda8(bf16x8 (&af)[8], const unsigned short* base, int aro){
  #pragma unroll
  for (int f = 0; f < 8; ++f)
    af[f] = ldb8((const unsigned short*)((const char*)base + aro + f * 1024));
}
__device__ __forceinline__ void ldb2(bf16x8 (&bf)[2], const unsigned short* base, int bro, int nh){
  #pragma unroll
  for (int g2 = 0; g2 < 2; ++g2)
    bf[g2] = ldb8((const unsigned short*)((const char*)base + bro + (nh * 2 + g2) * 1024));
}
__device__ __forceinline__ void mm_half(f32x4 (&acc)[8][4], const bf16x8 (&af)[8],
                                        const bf16x8 (&bf)[2], int nh, bool swp){
  if (swp){
    #pragma unroll
    for (int f = 0; f < 8; ++f)
      #pragma unroll
      for (int g2 = 0; g2 < 2; ++g2)
        acc[f][nh * 2 + g2] = mfma16(bf[g2], af[f], acc[f][nh * 2 + g2]);
  } else {
    #pragma unroll
    for (int f = 0; f < 8; ++f)
      #pragma unroll
      for (int g2 = 0; g2 < 2; ++g2)
        acc[f][nh * 2 + g2] = mfma16(af[f], bf[g2], acc[f][nh * 2 + g2]);
  }
}
__device__ __forceinline__ void stg_half(const char* src, int o, char* dst){
  gl_lds16(src + o, dst);
  gl_lds16(src + 131072 + o, dst + 8192);   // rows +128 (128 * 1024B)
}

#define BAR_() __builtin_amdgcn_s_barrier()
#define LGKM0_() do{ asm volatile("s_waitcnt lgkmcnt(0)" ::: "memory"); \
                     __builtin_amdgcn_sched_barrier(0); }while(0)
#define VM6_()   do{ asm volatile("s_waitcnt vmcnt(6)" ::: "memory"); \
                     __builtin_amdgcn_sched_barrier(0); }while(0)

__global__ __launch_bounds__(512) void k_gemm_uvqk(const unsigned short* __restrict__ A,
                                                   const unsigned short* __restrict__ BT,
                                                   const float* __restrict__ bias,
                                                   unsigned short* __restrict__ u_out,
                                                   unsigned short* __restrict__ vT,
                                                   unsigned short* __restrict__ qb,
                                                   unsigned short* __restrict__ kb){
  __shared__ __align__(16) unsigned short As[2][2][8192];   // [slot][kstep][256*32]
  __shared__ __align__(16) unsigned short Bs[2][2][8192];
  int tid = threadIdx.x;
  int lane = tid & 63;
  int lm = lane & 15, quad = lane >> 4;
  int w = tid >> 6;
  int wm = w & 1, wn = w >> 1;                 // 2(M) x 4(N) wave grid, wave tile 128x64
  int n0 = blockIdx.x * 256, m0 = blockIdx.y * 256;
  int cat = n0 >> 9;
  bool swp = (cat != 1);

  // staging source (pre-swizzled chunk): thread tid writes LDS row rs(+128), chunk-slot tid&3
  int rs = tid >> 2;
  int cs = ((tid & 3) ^ ((rs >> 1) & 3)) * 16;
  const char* aS = (const char*)(A  + (size_t)(m0 + rs) * Ec) + cs;
  const char* bS = (const char*)(BT + (size_t)(n0 + rs) * Ec) + cs;
  char* la00 = (char*)As[0][0] + tid * 16; char* la01 = (char*)As[0][1] + tid * 16;
  char* la10 = (char*)As[1][0] + tid * 16; char* la11 = (char*)As[1][1] + tid * 16;
  char* lb00 = (char*)Bs[0][0] + tid * 16; char* lb01 = (char*)Bs[0][1] + tid * 16;
  char* lb10 = (char*)Bs[1][0] + tid * 16; char* lb11 = (char*)Bs[1][1] + tid * 16;

  // ds_read fragment offsets (swizzled chunk, invariant across frags)
  int xq = (quad ^ ((lm >> 1) & 3)) * 16;
  int aro = (wm * 128 + lm) * 64 + xq;
  int bro = (wn * 64 + lm) * 64 + xq;

  f32x4 acc[8][4] = {};
  bf16x8 af[8], bf[2];

  // prologue: A0(0) B0(0) A1(0) B1(0) A0(1) B0(1) A1(1)  [14 loads]; vmcnt(6) lands tile 0
  stg_half(aS,   0, la00); stg_half(bS,   0, lb00);
  stg_half(aS,  64, la01); stg_half(bS,  64, lb01);
  stg_half(aS, 128, la10); stg_half(bS, 128, lb10);
  stg_half(aS, 192, la11);
  VM6_();
  BAR_();

  #pragma unroll 1
  for (int it = 0; it < 4; ++it){
    int b  = 2 * it + 1;
    int t2 = 2 * it + 2; if (t2 > 7) t2 = 7;   // clamp keeps vmcnt counts exact on last iter
    int t3 = 2 * it + 3; if (t3 > 7) t3 = 7;
    int ob1b = b  * 128 + 64;
    int o2   = t2 * 128;
    int o3   = t3 * 128;

    // ph1: tile a (k0,n0) | stage B1(b)
    lda8(af, As[0][0], aro); ldb2(bf, Bs[0][0], bro, 0); stg_half(bS, ob1b, lb11);
    BAR_(); LGKM0_();
    __builtin_amdgcn_s_setprio(1); mm_half(acc, af, bf, 0, swp); __builtin_amdgcn_s_setprio(0);
    BAR_();
    // ph2: tile a (k0,n1) | stage A0(t2)
    ldb2(bf, Bs[0][0], bro, 1); stg_half(aS, o2, la00);
    BAR_(); LGKM0_();
    __builtin_amdgcn_s_setprio(1); mm_half(acc, af, bf, 1, swp); __builtin_amdgcn_s_setprio(0);
    BAR_();
    // ph3: tile a (k1,n0) | stage B0(t2)
    lda8(af, As[0][1], aro); ldb2(bf, Bs[0][1], bro, 0); stg_half(bS, o2, lb00);
    BAR_(); LGKM0_();
    __builtin_amdgcn_s_setprio(1); mm_half(acc, af, bf, 0, swp); __builtin_amdgcn_s_setprio(0);
    BAR_();
    // ph4: tile a (k1,n1) | stage A1(t2) | vmcnt(6)
    ldb2(bf, Bs[0][1], bro, 1); stg_half(aS, o2 + 64, la01);
    VM6_(); BAR_(); LGKM0_();
    __builtin_amdgcn_s_setprio(1); mm_half(acc, af, bf, 1, swp); __builtin_amdgcn_s_setprio(0);
    BAR_();
    // ph5: tile b (k0,n0) | stage B1(t2)
    lda8(af, As[1][0], aro); ldb2(bf, Bs[1][0], bro, 0); stg_half(bS, o2 + 64, lb01);
    BAR_(); LGKM0_();
    __builtin_amdgcn_s_setprio(1); mm_half(acc, af, bf, 0, swp); __builtin_amdgcn_s_setprio(0);
    BAR_();
    // ph6: tile b (k0,n1) | stage A0(t3)
    ldb2(bf, Bs[1][0], bro, 1); stg_half(aS, o3, la10);
    BAR_(); LGKM0_();
    __builtin_amdgcn_s_setprio(1); mm_half(acc, af, bf, 1, swp); __builtin_amdgcn_s_setprio(0);
    BAR_();
    // ph7: tile b (k1,n0) | stage B0(t3)
    lda8(af, As[1][1], aro); ldb2(bf, Bs[1][1], bro, 0); stg_half(bS, o3, lb10);
    BAR_(); LGKM0_();
    __builtin_amdgcn_s_setprio(1); mm_half(acc, af, bf, 0, swp); __builtin_amdgcn_s_setprio(0);
    BAR_();
    // ph8: tile b (k1,n1) | stage A1(t3) | vmcnt(6)
    ldb2(bf, Bs[1][1], bro, 1); stg_half(aS, o3 + 64, la11);
    VM6_(); BAR_(); LGKM0_();
    __builtin_amdgcn_s_setprio(1); mm_half(acc, af, bf, 1, swp); __builtin_amdgcn_s_setprio(0);
    BAR_();
  }

  if (cat == 1){
    #pragma unroll
    for (int g = 0; g < 4; ++g){
      int colg = n0 + wn * 64 + g * 16 + lm;
      float bv = bias[colg];
      int c = colg & 511, h = c >> 6, d = c & 63;
      #pragma unroll
      for (int f = 0; f < 8; ++f){
        int row = m0 + wm * 128 + f * 16 + quad * 4;
        int bb_ = row >> 11, sr = row & (Sc - 1);
        s4v pv = pk4(silu_f(acc[f][g][0] + bv), silu_f(acc[f][g][1] + bv),
                     silu_f(acc[f][g][2] + bv), silu_f(acc[f][g][3] + bv));
        *(s4v*)(vT + ((size_t)(bb_ * Hc + h) * Dc + d) * Sc + sr) = pv;
      }
    }
  } else {
    #pragma unroll
    for (int f = 0; f < 8; ++f){
      int row = m0 + wm * 128 + f * 16 + lm;
      int bb_ = row >> 11, sr = row & (Sc - 1);
      #pragma unroll
      for (int g = 0; g < 4; ++g){
        int colg = n0 + wn * 64 + g * 16 + quad * 4;
        float4 bv = *(const float4*)(bias + colg);
        float v0 = silu_f(acc[f][g][0] + bv.x);
        float v1 = silu_f(acc[f][g][1] + bv.y);
        float v2 = silu_f(acc[f][g][2] + bv.z);
        float v3 = silu_f(acc[f][g][3] + bv.w);
        int c = colg & 511, h = c >> 6, d = c & 63;
        if (cat == 0){
          *(s4v*)(u_out + (size_t)row * Ec + c) = pk4(v0, v1, v2, v3);
        } else if (cat == 2){
          *(s4v*)(qb + ((size_t)(bb_ * Hc + h) * Sc + sr) * Dc + d) =
            pk4(v0 * 0.125f, v1 * 0.125f, v2 * 0.125f, v3 * 0.125f);
        } else {
          *(s4v*)(kb + ((size_t)(bb_ * Hc + h) * Sc + sr) * Dc + d) = pk4(v0, v1, v2, v3);
        }
      }
    }
  }
}

// ---------------- HSTU silu attention: swizzled DMA K/V tiles, double-buffered ----------------
__global__ __launch_bounds__(256) void k_attn(const unsigned short* __restrict__ qb,
                                              const unsigned short* __restrict__ kb,
                                              const unsigned short* __restrict__ vT,
                                              unsigned short* __restrict__ att){
  __shared__ __align__(16) unsigned short Kb[2][64 * 64];
  __shared__ __align__(16) unsigned short Vb[2][64 * 64];
  int tid = threadIdx.x;
  int lane = tid & 63, w = tid >> 6;
  int lm = lane & 15, quad = lane >> 4;
  int lmx = lm & 7;
  int bh = blockIdx.x;
  int qblk = 31 - blockIdx.y;              // heavy blocks first (tail balance)
  int qrow = qblk * 64 + w * 16;
  int lastT = qblk;
  int ntiles = lastT + 1;

  const unsigned short* kbp = kb + (size_t)bh * Sc * Dc;
  const unsigned short* vbp = vT + (size_t)bh * Dc * Sc;
  const unsigned short* qp = qb + ((size_t)bh * Sc + qrow + lm) * Dc + quad * 8;
  bf16x8 qa0 = ldb8(qp), qa1 = ldb8(qp + 32);

  int r0s = tid >> 3, c0s = ((tid & 7) ^ (r0s & 7)) * 16;
  int r1s = (tid + 256) >> 3, c1s = (((tid + 256) & 7) ^ (r1s & 7)) * 16;
  const char* kS0 = (const char*)kbp + (size_t)r0s * 128 + c0s;
  const char* kS1 = (const char*)kbp + (size_t)r1s * 128 + c1s;
  const char* vS0 = (const char*)vbp + (size_t)r0s * (Sc * 2) + c0s;
  const char* vS1 = (const char*)vbp + (size_t)r1s * (Sc * 2) + c1s;

  { // prologue: stage tile 0
    gl_lds16(kS0, (char*)Kb[0] + tid * 16);
    gl_lds16(kS1, (char*)Kb[0] + tid * 16 + 4096);
    gl_lds16(vS0, (char*)Vb[0] + tid * 16);
    gl_lds16(vS1, (char*)Vb[0] + tid * 16 + 4096);
  }
  __syncthreads();

  f32x4 o[4] = {};
  int qg = qrow + lm;
  for (int kt = 0; kt < ntiles; ++kt){
    int cur = kt & 1, nb = cur ^ 1;
    if (kt + 1 < ntiles){
      int knb = (kt + 1) * 128;   // key offset in bytes
      gl_lds16(kS0 + (size_t)(kt + 1) * 8192, (char*)Kb[nb] + tid * 16);
      gl_lds16(kS1 + (size_t)(kt + 1) * 8192, (char*)Kb[nb] + tid * 16 + 4096);
      gl_lds16(vS0 + knb, (char*)Vb[nb] + tid * 16);
      gl_lds16(vS1 + knb, (char*)Vb[nb] + tid * 16 + 4096);
    }
    const unsigned short* Kc = Kb[cur];
    const unsigned short* Vc = Vb[cur];
    bool maskT = (kt == lastT);
    int key0 = kt * 64;
    #pragma unroll
    for (int s = 0; s < 4; ++s){
      int krow = (s * 16 + lm) * 8;
      bf16x8 kf0 = ldb8(Kc + (krow + (quad ^ lmx)) * 8);
      bf16x8 kf1 = ldb8(Kc + (krow + ((quad + 4) ^ lmx)) * 8);
      f32x4 sc = {0.f, 0.f, 0.f, 0.f};
      sc = mfma16(kf0, qa0, sc);
      sc = mfma16(kf1, qa1, sc);
      s4v pf;
      if (maskT){
        float m[4];
        #pragma unroll
        for (int r = 0; r < 4; ++r){
          int kg = key0 + s * 16 + quad * 4 + r;
          bool ok = (kg <= qg) && ((kg < HISTc) || (kg == qg));
          m[r] = ok ? silu_f(sc[r]) : 0.f;
        }
        pf = pk4(m[0], m[1], m[2], m[3]);
      } else {
        pf = pk4(silu_f(sc[0]), silu_f(sc[1]), silu_f(sc[2]), silu_f(sc[3]));
      }
      #pragma unroll
      for (int t = 0; t < 4; ++t){
        int vrow = (t * 16 + lm) * 8;
        s4v vf = *(const s4v*)(Vc + (vrow + ((2 * s + (quad >> 1)) ^ lmx)) * 8 + (quad & 1) * 4);
        o[t] = __builtin_amdgcn_mfma_f32_16x16x16bf16_1k(pf, vf, o[t], 0, 0, 0);
      }
    }
    __syncthreads();
  }
  int bb_ = bh >> 3, hh = bh & 7;
  #pragma unroll
  for (int t = 0; t < 4; ++t){
    int d = t * 16 + lm;
    unsigned int p01 = pkbf(o[t][0] * (1.f / Sc), o[t][1] * (1.f / Sc));
    unsigned int p23 = pkbf(o[t][2] * (1.f / Sc), o[t][3] * (1.f / Sc));
    size_t base = ((size_t)(bb_ * Sc + qrow + quad * 4) * Hc + hh) * Dc + d;
    att[base]               = (unsigned short)p01;
    att[base + Hc * Dc]     = (unsigned short)(p01 >> 16);
    att[base + 2 * Hc * Dc] = (unsigned short)p23;
    att[base + 3 * Hc * Dc] = (unsigned short)(p23 >> 16);
  }
}

// ---------------- GEMM2: out = par @ w_proj + x (staged, swizzled, C^T epilogue) ----------------
__global__ __launch_bounds__(256) void k_gemm_proj(const unsigned short* __restrict__ A,
                                                   const unsigned short* __restrict__ BT,
                                                   const float* __restrict__ x,
                                                   float* __restrict__ out){
  __shared__ __align__(16) unsigned short As[2][128 * 32];
  __shared__ __align__(16) unsigned short Bs[2][128 * 32];
  int tid = threadIdx.x;
  int lane = tid & 63, w = tid >> 6;
  int lm = lane & 15, quad = lane >> 4;
  int wm = w & 1, wn = w >> 1;
  int n0 = blockIdx.x * 128, m0 = blockIdx.y * 128;
  int lmx = lm & 3;

  int r0s = tid >> 2, c0s = ((tid & 3) ^ (r0s & 3)) * 16;
  int r1s = (tid + 256) >> 2, c1s = (((tid + 256) & 3) ^ (r1s & 3)) * 16;
  const char* saA0 = (const char*)(A  + (size_t)(m0 + r0s) * Ec) + c0s;
  const char* saA1 = (const char*)(A  + (size_t)(m0 + r1s) * Ec) + c1s;
  const char* saB0 = (const char*)(BT + (size_t)(n0 + r0s) * Ec) + c0s;
  const char* saB1 = (const char*)(BT + (size_t)(n0 + r1s) * Ec) + c1s;

  gl_lds16(saA0, (char*)As[0] + tid * 16);
  gl_lds16(saA1, (char*)As[0] + tid * 16 + 4096);
  gl_lds16(saB0, (char*)Bs[0] + tid * 16);
  gl_lds16(saB1, (char*)Bs[0] + tid * 16 + 4096);
  __syncthreads();

  f32x4 acc[4][4] = {};
  #pragma unroll 1
  for (int kt = 0; kt < 16; ++kt){
    int cur = kt & 1, nb = cur ^ 1;
    if (kt < 15){
      int k0 = (kt + 1) * 64;   // bytes
      gl_lds16(saA0 + k0, (char*)As[nb] + tid * 16);
      gl_lds16(saA1 + k0, (char*)As[nb] + tid * 16 + 4096);
      gl_lds16(saB0 + k0, (char*)Bs[nb] + tid * 16);
      gl_lds16(saB1 + k0, (char*)Bs[nb] + tid * 16 + 4096);
    }
    bf16x8 af[4], bfr[4];
    #pragma unroll
    for (int s = 0; s < 4; ++s)
      af[s]  = ldb8(As[cur] + ((wm * 64 + s * 16 + lm) * 4 + (quad ^ lmx)) * 8);
    #pragma unroll
    for (int t = 0; t < 4; ++t)
      bfr[t] = ldb8(Bs[cur] + ((wn * 64 + t * 16 + lm) * 4 + (quad ^ lmx)) * 8);
    #pragma unroll
    for (int s = 0; s < 4; ++s)
      #pragma unroll
      for (int t = 0; t < 4; ++t)
        acc[s][t] = mfma16(bfr[t], af[s], acc[s][t]);   // C^T orientation
    __syncthreads();
  }

  #pragma unroll
  for (int s = 0; s < 4; ++s){
    int row = m0 + wm * 64 + s * 16 + lm;
    #pragma unroll
    for (int t = 0; t < 4; ++t){
      int col = n0 + wn * 64 + t * 16 + quad * 4;
      float4 xr = *(const float4*)(x + (size_t)row * Ec + col);
      float4 o4 = {acc[s][t][0] + xr.x, acc[s][t][1] + xr.y,
                   acc[s][t][2] + xr.z, acc[s][t][3] + xr.w};
      *(float4*)(out + (size_t)row * Ec + col) = o4;
    }
  }
}

extern "C" void kernel_launch(void* const* d_in, const int* in_sizes, int n_in,
                              void* d_out, int out_size, void* d_ws, size_t ws_size,
                              hipStream_t stream){
  (void)in_sizes; (void)n_in; (void)out_size; (void)ws_size;
  const float* x        = (const float*)d_in[0];
  const float* w_uvqk   = (const float*)d_in[1];
  const float* b_uvqk   = (const float*)d_in[2];
  const float* ln_in_w  = (const float*)d_in[3];
  const float* ln_in_b  = (const float*)d_in[4];
  const float* ln_out_w = (const float*)d_in[5];
  const float* ln_out_b = (const float*)d_in[6];
  const float* w_proj   = (const float*)d_in[7];
  float* out = (float*)d_out;

  char* ws = (char*)d_ws;
  unsigned short* xn  = (unsigned short*)(ws + 0);          // 16 MB, reused as `par` later
  unsigned short* wuT = (unsigned short*)(ws + 16777216);   // 2 MB
  unsigned short* wpT = (unsigned short*)(ws + 18874368);   // 0.5 MB
  unsigned short* ub  = (unsigned short*)(ws + 19398656);   // 16 MB (bf16)
  unsigned short* qbf = (unsigned short*)(ws + 52953088);   // 16 MB
  unsigned short* kbf = (unsigned short*)(ws + 69730304);   // 16 MB
  unsigned short* vTt = (unsigned short*)(ws + 86507520);   // 16 MB
  unsigned short* att = (unsigned short*)(ws + 103284736);  // 16 MB (bf16)

  dim3 tb(32, 32);
  k_transpose_cast<<<dim3(N1c / 32, Ec / 32), tb, 0, stream>>>(w_uvqk, wuT, Ec, N1c);
  k_transpose_cast<<<dim3(Ec / 32, Ec / 32), tb, 0, stream>>>(w_proj, wpT, Ec, Ec);
  k_ln_in<<<Tc / 4, 256, 0, stream>>>(x, ln_in_w, ln_in_b, xn);
  k_gemm_uvqk<<<dim3(N1c / 256, Tc / 256), 512, 0, stream>>>(xn, wuT, b_uvqk, ub, vTt, qbf, kbf);
  k_attn<<<dim3(Bc * Hc, Sc / 64), 256, 0, stream>>>(qbf, kbf, vTt, att);
  k_ln_mul<<<Tc / 4, 256, 0, stream>>>(att, ln_out_w, ln_out_b, ub, xn);
  k_gemm_proj<<<dim3(Ec / 128, Tc / 128), 256, 0, stream>>>(xn, wpT, x, out);
}

// Round 2
// 303.755 us; speedup vs baseline: 1.0518x; 1.0518x over previous
//
#include <hip/hip_runtime.h>
#include <hip/hip_bf16.h>

#define Bc 8
#define Sc 2048
#define Hc 8
#define Dc 64
#define Ec 512
#define NTc 64
#define Tc (Bc*Sc)
#define N1c (4*Hc*Dc)
#define HISTc (Sc - NTc)

typedef float f32x4 __attribute__((ext_vector_type(4)));
typedef __bf16 bf16x8 __attribute__((ext_vector_type(8)));
typedef short short8 __attribute__((ext_vector_type(8)));
typedef short s4v __attribute__((ext_vector_type(4)));

__device__ __forceinline__ unsigned short f2bf(float f){
  unsigned int u = __float_as_uint(f);
  u += 0x7fffu + ((u >> 16) & 1u);
  return (unsigned short)(u >> 16);
}
__device__ __forceinline__ float bf2f(unsigned short h){
  return __uint_as_float(((unsigned int)h) << 16);
}
// packed f32x2 -> bf16x2 (v_cvt_pk_bf16_f32)
__device__ __forceinline__ unsigned int pkbf(float a, float b){
  float2 f; f.x = a; f.y = b;
  __hip_bfloat162 h = __float22bfloat162_rn(f);
  unsigned int u;
  __builtin_memcpy(&u, &h, 4);
  return u;
}
__device__ __forceinline__ s4v pk4(float a, float b, float c, float d){
  uint2 u; u.x = pkbf(a, b); u.y = pkbf(c, d);
  return __builtin_bit_cast(s4v, u);
}
__device__ __forceinline__ float silu_f(float x){
  return x * __builtin_amdgcn_rcpf(1.f + __expf(-x));
}
__device__ __forceinline__ bf16x8 ldb8(const unsigned short* p){
  return __builtin_bit_cast(bf16x8, *(const short8*)p);
}
__device__ __forceinline__ f32x4 mfma16(bf16x8 a, bf16x8 b, f32x4 c){
  return __builtin_amdgcn_mfma_f32_16x16x32_bf16(a, b, c, 0, 0, 0);
}
__device__ __forceinline__ void gl_lds16(const void* g, void* l){
  __builtin_amdgcn_global_load_lds((const __attribute__((address_space(1))) unsigned int*)g,
                                   (__attribute__((address_space(3))) unsigned int*)l, 16, 0, 0);
}

// ---------------- transpose + cast fp32 -> bf16 : out[c][r] = in[r][c] ----------------
__global__ __launch_bounds__(1024) void k_transpose_cast(const float* __restrict__ in,
                                                         unsigned short* __restrict__ out,
                                                         int R, int C){
  __shared__ float tile[32][33];
  int tx = threadIdx.x, ty = threadIdx.y;
  int c0 = blockIdx.x * 32, r0 = blockIdx.y * 32;
  tile[ty][tx] = in[(size_t)(r0 + ty) * C + c0 + tx];
  __syncthreads();
  out[(size_t)(c0 + ty) * R + r0 + tx] = f2bf(tile[tx][ty]);
}

// ---------------- input layernorm -> bf16 (one wave per row of 512) ----------------
__global__ __launch_bounds__(256) void k_ln_in(const float* __restrict__ x, const float* __restrict__ g,
                                               const float* __restrict__ b, unsigned short* __restrict__ xn){
  int lane = threadIdx.x & 63;
  int row = blockIdx.x * 4 + (threadIdx.x >> 6);
  const float* xr = x + (size_t)row * Ec + lane * 8;
  float4 v0 = *(const float4*)xr;
  float4 v1 = *(const float4*)(xr + 4);
  float vv[8] = {v0.x, v0.y, v0.z, v0.w, v1.x, v1.y, v1.z, v1.w};
  float s = 0.f, ss = 0.f;
  #pragma unroll
  for (int j = 0; j < 8; ++j){ s += vv[j]; ss += vv[j] * vv[j]; }
  #pragma unroll
  for (int m = 1; m < 64; m <<= 1){ s += __shfl_xor(s, m); ss += __shfl_xor(ss, m); }
  float mu = s * (1.f / Ec);
  float rs = rsqrtf(ss * (1.f / Ec) - mu * mu + 1e-5f);
  int c = lane * 8;
  float o[8];
  #pragma unroll
  for (int j = 0; j < 8; ++j) o[j] = (vv[j] - mu) * rs * g[c + j] + b[c + j];
  uint4 pk; pk.x = pkbf(o[0], o[1]); pk.y = pkbf(o[2], o[3]);
  pk.z = pkbf(o[4], o[5]); pk.w = pkbf(o[6], o[7]);
  *(uint4*)(xn + (size_t)row * Ec + c) = pk;
}

// ---------------- ln(attn_out) * u -> bf16 (att and u are bf16) ----------------
__global__ __launch_bounds__(256) void k_ln_mul(const unsigned short* __restrict__ att, const float* __restrict__ g,
                                                const float* __restrict__ b, const unsigned short* __restrict__ u,
                                                unsigned short* __restrict__ par){
  int lane = threadIdx.x & 63;
  int row = blockIdx.x * 4 + (threadIdx.x >> 6);
  short8 a8 = *(const short8*)(att + (size_t)row * Ec + lane * 8);
  short8 u8 = *(const short8*)(u + (size_t)row * Ec + lane * 8);
  float vv[8];
  #pragma unroll
  for (int j = 0; j < 8; ++j) vv[j] = bf2f((unsigned short)a8[j]);
  float s = 0.f, ss = 0.f;
  #pragma unroll
  for (int j = 0; j < 8; ++j){ s += vv[j]; ss += vv[j] * vv[j]; }
  #pragma unroll
  for (int m = 1; m < 64; m <<= 1){ s += __shfl_xor(s, m); ss += __shfl_xor(ss, m); }
  float mu = s * (1.f / Ec);
  float rs = rsqrtf(ss * (1.f / Ec) - mu * mu + 1e-5f);
  int c = lane * 8;
  float o[8];
  #pragma unroll
  for (int j = 0; j < 8; ++j){
    float uu = bf2f((unsigned short)u8[j]);
    o[j] = uu * ((vv[j] - mu) * rs * g[c + j] + b[c + j]);
  }
  uint4 pk; pk.x = pkbf(o[0], o[1]); pk.y = pkbf(o[2], o[3]);
  pk.z = pkbf(o[4], o[5]); pk.w = pkbf(o[6], o[7]);
  *(uint4*)(par + (size_t)row * Ec + c) = pk;
}

// ---------------- GEMM1: 128x128 2-phase, A via LDS (dbuf), B direct from L2 ----------------
// B (w_uvqk^T, 2MB) is L2-resident -> register loads, no LDS staging (halves barrier-drained
// bytes, LDS 32->16KB). XCD swizzle: all 16 n-blocks of an m-panel on one XCD (A L2-resident,
// 2MB/XCD). A-swizzle store/read pair uses (row>>1)&3 -> max 2-way bank aliasing (free).
__global__ __launch_bounds__(256) void k_gemm_uvqk(const unsigned short* __restrict__ A,
                                                   const unsigned short* __restrict__ BT,
                                                   const float* __restrict__ bias,
                                                   unsigned short* __restrict__ u_out,
                                                   unsigned short* __restrict__ vT,
                                                   unsigned short* __restrict__ qb,
                                                   unsigned short* __restrict__ kb){
  __shared__ __align__(16) unsigned short As[2][128 * 32];
  int tid = threadIdx.x;
  int lane = tid & 63, w = tid >> 6;
  int lm = lane & 15, quad = lane >> 4;
  int wm = w & 1, wn = w >> 1;
  int bid = blockIdx.y * gridDim.x + blockIdx.x;       // hw linear id (x fastest)
  int id2 = (bid & 7) * 256 + (bid >> 3);              // bijective XCD swizzle, nwg=2048
  int n0 = (id2 & 15) << 7, m0 = (id2 >> 4) << 7;
  int cat = n0 >> 9;
  bool swp = (cat != 1);

  int r0s = tid >> 2, c0s = ((tid & 3) ^ ((r0s >> 1) & 3)) * 16;
  int r1s = r0s + 64;                                  // (r1s>>1)&3 == (r0s>>1)&3
  const char* saA0 = (const char*)(A + (size_t)(m0 + r0s) * Ec) + c0s;
  const char* saA1 = (const char*)(A + (size_t)(m0 + r1s) * Ec) + c0s;
  const unsigned short* Bp = BT + (size_t)(n0 + wn * 64 + lm) * Ec + quad * 8;

  gl_lds16(saA0, (char*)As[0] + tid * 16);
  gl_lds16(saA1, (char*)As[0] + tid * 16 + 4096);
  __syncthreads();

  f32x4 acc[4][4] = {};
  #pragma unroll 1
  for (int kt = 0; kt < 16; ++kt){
    int cur = kt & 1, nb = cur ^ 1;
    bf16x8 bfr[4];
    #pragma unroll
    for (int t = 0; t < 4; ++t)
      bfr[t] = ldb8(Bp + (size_t)t * 16 * Ec + kt * 32);
    if (kt < 15){
      int k0 = (kt + 1) * 64;   // bytes
      gl_lds16(saA0 + k0, (char*)As[nb] + tid * 16);
      gl_lds16(saA1 + k0, (char*)As[nb] + tid * 16 + 4096);
    }
    bf16x8 af[4];
    #pragma unroll
    for (int s = 0; s < 4; ++s)
      af[s] = ldb8(As[cur] + ((wm * 64 + s * 16 + lm) * 4 + (quad ^ ((lm >> 1) & 3))) * 8);
    if (swp){
      #pragma unroll
      for (int s = 0; s < 4; ++s)
        #pragma unroll
        for (int t = 0; t < 4; ++t)
          acc[s][t] = mfma16(bfr[t], af[s], acc[s][t]);
    } else {
      #pragma unroll
      for (int s = 0; s < 4; ++s)
        #pragma unroll
        for (int t = 0; t < 4; ++t)
          acc[s][t] = mfma16(af[s], bfr[t], acc[s][t]);
    }
    __syncthreads();
  }

  if (cat == 1){
    #pragma unroll
    for (int t = 0; t < 4; ++t){
      int colg = n0 + wn * 64 + t * 16 + lm;
      float bv = bias[colg];
      int c = colg & 511, h = c >> 6, d = c & 63;
      #pragma unroll
      for (int s = 0; s < 4; ++s){
        int row = m0 + wm * 64 + s * 16 + quad * 4;
        int bb_ = row >> 11, sr = row & (Sc - 1);
        s4v pv = pk4(silu_f(acc[s][t][0] + bv), silu_f(acc[s][t][1] + bv),
                     silu_f(acc[s][t][2] + bv), silu_f(acc[s][t][3] + bv));
        *(s4v*)(vT + ((size_t)(bb_ * Hc + h) * Dc + d) * Sc + sr) = pv;
      }
    }
  } else {
    #pragma unroll
    for (int s = 0; s < 4; ++s){
      int row = m0 + wm * 64 + s * 16 + lm;
      int bb_ = row >> 11, sr = row & (Sc - 1);
      #pragma unroll
      for (int t = 0; t < 4; ++t){
        int colg = n0 + wn * 64 + t * 16 + quad * 4;
        float4 bv = *(const float4*)(bias + colg);
        float v0 = silu_f(acc[s][t][0] + bv.x);
        float v1 = silu_f(acc[s][t][1] + bv.y);
        float v2 = silu_f(acc[s][t][2] + bv.z);
        float v3 = silu_f(acc[s][t][3] + bv.w);
        int c = colg & 511, h = c >> 6, d = c & 63;
        if (cat == 0){
          *(s4v*)(u_out + (size_t)row * Ec + c) = pk4(v0, v1, v2, v3);
        } else if (cat == 2){
          *(s4v*)(qb + ((size_t)(bb_ * Hc + h) * Sc + sr) * Dc + d) =
            pk4(v0 * 0.125f, v1 * 0.125f, v2 * 0.125f, v3 * 0.125f);
        } else {
          *(s4v*)(kb + ((size_t)(bb_ * Hc + h) * Sc + sr) * Dc + d) = pk4(v0, v1, v2, v3);
        }
      }
    }
  }
}

// ---------------- HSTU silu attention: swizzled DMA K/V tiles, double-buffered ----------------
__global__ __launch_bounds__(256) void k_attn(const unsigned short* __restrict__ qb,
                                              const unsigned short* __restrict__ kb,
                                              const unsigned short* __restrict__ vT,
                                              unsigned short* __restrict__ att){
  __shared__ __align__(16) unsigned short Kb[2][64 * 64];
  __shared__ __align__(16) unsigned short Vb[2][64 * 64];
  int tid = threadIdx.x;
  int lane = tid & 63, w = tid >> 6;
  int lm = lane & 15, quad = lane >> 4;
  int lmx = lm & 7;
  int bh = blockIdx.x;
  int qblk = 31 - blockIdx.y;              // heavy blocks first (tail balance)
  int qrow = qblk * 64 + w * 16;
  int lastT = qblk;
  int ntiles = lastT + 1;

  const unsigned short* kbp = kb + (size_t)bh * Sc * Dc;
  const unsigned short* vbp = vT + (size_t)bh * Dc * Sc;
  const unsigned short* qp = qb + ((size_t)bh * Sc + qrow + lm) * Dc + quad * 8;
  bf16x8 qa0 = ldb8(qp), qa1 = ldb8(qp + 32);

  int r0s = tid >> 3, c0s = ((tid & 7) ^ (r0s & 7)) * 16;
  int r1s = (tid + 256) >> 3, c1s = (((tid + 256) & 7) ^ (r1s & 7)) * 16;
  const char* kS0 = (const char*)kbp + (size_t)r0s * 128 + c0s;
  const char* kS1 = (const char*)kbp + (size_t)r1s * 128 + c1s;
  const char* vS0 = (const char*)vbp + (size_t)r0s * (Sc * 2) + c0s;
  const char* vS1 = (const char*)vbp + (size_t)r1s * (Sc * 2) + c1s;

  { // prologue: stage tile 0
    gl_lds16(kS0, (char*)Kb[0] + tid * 16);
    gl_lds16(kS1, (char*)Kb[0] + tid * 16 + 4096);
    gl_lds16(vS0, (char*)Vb[0] + tid * 16);
    gl_lds16(vS1, (char*)Vb[0] + tid * 16 + 4096);
  }
  __syncthreads();

  f32x4 o[4] = {};
  int qg = qrow + lm;
  for (int kt = 0; kt < ntiles; ++kt){
    int cur = kt & 1, nb = cur ^ 1;
    if (kt + 1 < ntiles){
      int knb = (kt + 1) * 128;   // key offset in bytes
      gl_lds16(kS0 + (size_t)(kt + 1) * 8192, (char*)Kb[nb] + tid * 16);
      gl_lds16(kS1 + (size_t)(kt + 1) * 8192, (char*)Kb[nb] + tid * 16 + 4096);
      gl_lds16(vS0 + knb, (char*)Vb[nb] + tid * 16);
      gl_lds16(vS1 + knb, (char*)Vb[nb] + tid * 16 + 4096);
    }
    const unsigned short* Kc = Kb[cur];
    const unsigned short* Vc = Vb[cur];
    bool maskT = (kt == lastT);
    int key0 = kt * 64;
    #pragma unroll
    for (int s = 0; s < 4; ++s){
      int krow = (s * 16 + lm) * 8;
      bf16x8 kf0 = ldb8(Kc + (krow + (quad ^ lmx)) * 8);
      bf16x8 kf1 = ldb8(Kc + (krow + ((quad + 4) ^ lmx)) * 8);
      f32x4 sc = {0.f, 0.f, 0.f, 0.f};
      sc = mfma16(kf0, qa0, sc);
      sc = mfma16(kf1, qa1, sc);
      s4v pf;
      if (maskT){
        float m[4];
        #pragma unroll
        for (int r = 0; r < 4; ++r){
          int kg = key0 + s * 16 + quad * 4 + r;
          bool ok = (kg <= qg) && ((kg < HISTc) || (kg == qg));
          m[r] = ok ? silu_f(sc[r]) : 0.f;
        }
        pf = pk4(m[0], m[1], m[2], m[3]);
      } else {
        pf = pk4(silu_f(sc[0]), silu_f(sc[1]), silu_f(sc[2]), silu_f(sc[3]));
      }
      #pragma unroll
      for (int t = 0; t < 4; ++t){
        int vrow = (t * 16 + lm) * 8;
        s4v vf = *(const s4v*)(Vc + (vrow + ((2 * s + (quad >> 1)) ^ lmx)) * 8 + (quad & 1) * 4);
        o[t] = __builtin_amdgcn_mfma_f32_16x16x16bf16_1k(pf, vf, o[t], 0, 0, 0);
      }
    }
    __syncthreads();
  }
  int bb_ = bh >> 3, hh = bh & 7;
  #pragma unroll
  for (int t = 0; t < 4; ++t){
    int d = t * 16 + lm;
    unsigned int p01 = pkbf(o[t][0] * (1.f / Sc), o[t][1] * (1.f / Sc));
    unsigned int p23 = pkbf(o[t][2] * (1.f / Sc), o[t][3] * (1.f / Sc));
    size_t base = ((size_t)(bb_ * Sc + qrow + quad * 4) * Hc + hh) * Dc + d;
    att[base]               = (unsigned short)p01;
    att[base + Hc * Dc]     = (unsigned short)(p01 >> 16);
    att[base + 2 * Hc * Dc] = (unsigned short)p23;
    att[base + 3 * Hc * Dc] = (unsigned short)(p23 >> 16);
  }
}

// ---------------- GEMM2: out = par @ w_proj + x (A LDS dbuf, B direct, C^T epilogue) ----------------
__global__ __launch_bounds__(256) void k_gemm_proj(const unsigned short* __restrict__ A,
                                                   const unsigned short* __restrict__ BT,
                                                   const float* __restrict__ x,
                                                   float* __restrict__ out){
  __shared__ __align__(16) unsigned short As[2][128 * 32];
  int tid = threadIdx.x;
  int lane = tid & 63, w = tid >> 6;
  int lm = lane & 15, quad = lane >> 4;
  int wm = w & 1, wn = w >> 1;
  int bid = blockIdx.y * gridDim.x + blockIdx.x;       // nwg = 512
  int id2 = (bid & 7) * 64 + (bid >> 3);               // bijective XCD swizzle
  int n0 = (id2 & 3) << 7, m0 = (id2 >> 2) << 7;

  int r0s = tid >> 2, c0s = ((tid & 3) ^ ((r0s >> 1) & 3)) * 16;
  int r1s = r0s + 64;
  const char* saA0 = (const char*)(A + (size_t)(m0 + r0s) * Ec) + c0s;
  const char* saA1 = (const char*)(A + (size_t)(m0 + r1s) * Ec) + c0s;
  const unsigned short* Bp = BT + (size_t)(n0 + wn * 64 + lm) * Ec + quad * 8;

  gl_lds16(saA0, (char*)As[0] + tid * 16);
  gl_lds16(saA1, (char*)As[0] + tid * 16 + 4096);
  __syncthreads();

  f32x4 acc[4][4] = {};
  #pragma unroll 1
  for (int kt = 0; kt < 16; ++kt){
    int cur = kt & 1, nb = cur ^ 1;
    bf16x8 bfr[4];
    #pragma unroll
    for (int t = 0; t < 4; ++t)
      bfr[t] = ldb8(Bp + (size_t)t * 16 * Ec + kt * 32);
    if (kt < 15){
      int k0 = (kt + 1) * 64;   // bytes
      gl_lds16(saA0 + k0, (char*)As[nb] + tid * 16);
      gl_lds16(saA1 + k0, (char*)As[nb] + tid * 16 + 4096);
    }
    bf16x8 af[4];
    #pragma unroll
    for (int s = 0; s < 4; ++s)
      af[s] = ldb8(As[cur] + ((wm * 64 + s * 16 + lm) * 4 + (quad ^ ((lm >> 1) & 3))) * 8);
    #pragma unroll
    for (int s = 0; s < 4; ++s)
      #pragma unroll
      for (int t = 0; t < 4; ++t)
        acc[s][t] = mfma16(bfr[t], af[s], acc[s][t]);   // C^T orientation
    __syncthreads();
  }

  #pragma unroll
  for (int s = 0; s < 4; ++s){
    int row = m0 + wm * 64 + s * 16 + lm;
    #pragma unroll
    for (int t = 0; t < 4; ++t){
      int col = n0 + wn * 64 + t * 16 + quad * 4;
      float4 xr = *(const float4*)(x + (size_t)row * Ec + col);
      float4 o4 = {acc[s][t][0] + xr.x, acc[s][t][1] + xr.y,
                   acc[s][t][2] + xr.z, acc[s][t][3] + xr.w};
      *(float4*)(out + (size_t)row * Ec + col) = o4;
    }
  }
}

extern "C" void kernel_launch(void* const* d_in, const int* in_sizes, int n_in,
                              void* d_out, int out_size, void* d_ws, size_t ws_size,
                              hipStream_t stream){
  (void)in_sizes; (void)n_in; (void)out_size; (void)ws_size;
  const float* x        = (const float*)d_in[0];
  const float* w_uvqk   = (const float*)d_in[1];
  const float* b_uvqk   = (const float*)d_in[2];
  const float* ln_in_w  = (const float*)d_in[3];
  const float* ln_in_b  = (const float*)d_in[4];
  const float* ln_out_w = (const float*)d_in[5];
  const float* ln_out_b = (const float*)d_in[6];
  const float* w_proj   = (const float*)d_in[7];
  float* out = (float*)d_out;

  char* ws = (char*)d_ws;
  unsigned short* xn  = (unsigned short*)(ws + 0);          // 16 MB, reused as `par` later
  unsigned short* wuT = (unsigned short*)(ws + 16777216);   // 2 MB
  unsigned short* wpT = (unsigned short*)(ws + 18874368);   // 0.5 MB
  unsigned short* ub  = (unsigned short*)(ws + 19398656);   // 16 MB (bf16)
  unsigned short* qbf = (unsigned short*)(ws + 52953088);   // 16 MB
  unsigned short* kbf = (unsigned short*)(ws + 69730304);   // 16 MB
  unsigned short* vTt = (unsigned short*)(ws + 86507520);   // 16 MB
  unsigned short* att = (unsigned short*)(ws + 103284736);  // 16 MB (bf16)

  dim3 tb(32, 32);
  k_transpose_cast<<<dim3(N1c / 32, Ec / 32), tb, 0, stream>>>(w_uvqk, wuT, Ec, N1c);
  k_transpose_cast<<<dim3(Ec / 32, Ec / 32), tb, 0, stream>>>(w_proj, wpT, Ec, Ec);
  k_ln_in<<<Tc / 4, 256, 0, stream>>>(x, ln_in_w, ln_in_b, xn);
  k_gemm_uvqk<<<dim3(N1c / 128, Tc / 128), 256, 0, stream>>>(xn, wuT, b_uvqk, ub, vTt, qbf, kbf);
  k_attn<<<dim3(Bc * Hc, Sc / 64), 256, 0, stream>>>(qbf, kbf, vTt, att);
  k_ln_mul<<<Tc / 4, 256, 0, stream>>>(att, ln_out_w, ln_out_b, ub, xn);
  k_gemm_proj<<<dim3(Ec / 128, Tc / 128), 256, 0, stream>>>(xn, wpT, x, out);
}

// Round 3
// 293.476 us; speedup vs baseline: 1.0886x; 1.0350x over previous
//
#include <hip/hip_runtime.h>
#include <hip/hip_bf16.h>

#define Bc 8
#define Sc 2048
#define Hc 8
#define Dc 64
#define Ec 512
#define NTc 64
#define Tc (Bc*Sc)
#define N1c (4*Hc*Dc)
#define HISTc (Sc - NTc)

typedef float f32x4 __attribute__((ext_vector_type(4)));
typedef __bf16 bf16x8 __attribute__((ext_vector_type(8)));
typedef short short8 __attribute__((ext_vector_type(8)));
typedef short s4v __attribute__((ext_vector_type(4)));

__device__ __forceinline__ unsigned short f2bf(float f){
  unsigned int u = __float_as_uint(f);
  u += 0x7fffu + ((u >> 16) & 1u);
  return (unsigned short)(u >> 16);
}
__device__ __forceinline__ float bf2f(unsigned short h){
  return __uint_as_float(((unsigned int)h) << 16);
}
// packed f32x2 -> bf16x2 (v_cvt_pk_bf16_f32)
__device__ __forceinline__ unsigned int pkbf(float a, float b){
  float2 f; f.x = a; f.y = b;
  __hip_bfloat162 h = __float22bfloat162_rn(f);
  unsigned int u;
  __builtin_memcpy(&u, &h, 4);
  return u;
}
__device__ __forceinline__ s4v pk4(float a, float b, float c, float d){
  uint2 u; u.x = pkbf(a, b); u.y = pkbf(c, d);
  return __builtin_bit_cast(s4v, u);
}
__device__ __forceinline__ float silu_f(float x){
  return x * __builtin_amdgcn_rcpf(1.f + __expf(-x));
}
__device__ __forceinline__ bf16x8 ldb8(const unsigned short* p){
  return __builtin_bit_cast(bf16x8, *(const short8*)p);
}
__device__ __forceinline__ f32x4 mfma16(bf16x8 a, bf16x8 b, f32x4 c){
  return __builtin_amdgcn_mfma_f32_16x16x32_bf16(a, b, c, 0, 0, 0);
}
__device__ __forceinline__ void gl_lds16(const void* g, void* l){
  __builtin_amdgcn_global_load_lds((const __attribute__((address_space(1))) unsigned int*)g,
                                   (__attribute__((address_space(3))) unsigned int*)l, 16, 0, 0);
}

// ---------------- transpose + cast fp32 -> bf16 : out[c][r] = in[r][c] ----------------
__global__ __launch_bounds__(1024) void k_transpose_cast(const float* __restrict__ in,
                                                         unsigned short* __restrict__ out,
                                                         int R, int C){
  __shared__ float tile[32][33];
  int tx = threadIdx.x, ty = threadIdx.y;
  int c0 = blockIdx.x * 32, r0 = blockIdx.y * 32;
  tile[ty][tx] = in[(size_t)(r0 + ty) * C + c0 + tx];
  __syncthreads();
  out[(size_t)(c0 + ty) * R + r0 + tx] = f2bf(tile[tx][ty]);
}

// ---------------- input layernorm -> bf16 (one wave per row of 512) ----------------
__global__ __launch_bounds__(256) void k_ln_in(const float* __restrict__ x, const float* __restrict__ g,
                                               const float* __restrict__ b, unsigned short* __restrict__ xn){
  int lane = threadIdx.x & 63;
  int row = blockIdx.x * 4 + (threadIdx.x >> 6);
  const float* xr = x + (size_t)row * Ec + lane * 8;
  float4 v0 = *(const float4*)xr;
  float4 v1 = *(const float4*)(xr + 4);
  float vv[8] = {v0.x, v0.y, v0.z, v0.w, v1.x, v1.y, v1.z, v1.w};
  float s = 0.f, ss = 0.f;
  #pragma unroll
  for (int j = 0; j < 8; ++j){ s += vv[j]; ss += vv[j] * vv[j]; }
  #pragma unroll
  for (int m = 1; m < 64; m <<= 1){ s += __shfl_xor(s, m); ss += __shfl_xor(ss, m); }
  float mu = s * (1.f / Ec);
  float rs = rsqrtf(ss * (1.f / Ec) - mu * mu + 1e-5f);
  int c = lane * 8;
  float o[8];
  #pragma unroll
  for (int j = 0; j < 8; ++j) o[j] = (vv[j] - mu) * rs * g[c + j] + b[c + j];
  uint4 pk; pk.x = pkbf(o[0], o[1]); pk.y = pkbf(o[2], o[3]);
  pk.z = pkbf(o[4], o[5]); pk.w = pkbf(o[6], o[7]);
  *(uint4*)(xn + (size_t)row * Ec + c) = pk;
}

// ---------------- ln(attn_out) * u -> bf16 (att and u are bf16) ----------------
__global__ __launch_bounds__(256) void k_ln_mul(const unsigned short* __restrict__ att, const float* __restrict__ g,
                                                const float* __restrict__ b, const unsigned short* __restrict__ u,
                                                unsigned short* __restrict__ par){
  int lane = threadIdx.x & 63;
  int row = blockIdx.x * 4 + (threadIdx.x >> 6);
  short8 a8 = *(const short8*)(att + (size_t)row * Ec + lane * 8);
  short8 u8 = *(const short8*)(u + (size_t)row * Ec + lane * 8);
  float vv[8];
  #pragma unroll
  for (int j = 0; j < 8; ++j) vv[j] = bf2f((unsigned short)a8[j]);
  float s = 0.f, ss = 0.f;
  #pragma unroll
  for (int j = 0; j < 8; ++j){ s += vv[j]; ss += vv[j] * vv[j]; }
  #pragma unroll
  for (int m = 1; m < 64; m <<= 1){ s += __shfl_xor(s, m); ss += __shfl_xor(ss, m); }
  float mu = s * (1.f / Ec);
  float rs = rsqrtf(ss * (1.f / Ec) - mu * mu + 1e-5f);
  int c = lane * 8;
  float o[8];
  #pragma unroll
  for (int j = 0; j < 8; ++j){
    float uu = bf2f((unsigned short)u8[j]);
    o[j] = uu * ((vv[j] - mu) * rs * g[c + j] + b[c + j]);
  }
  uint4 pk; pk.x = pkbf(o[0], o[1]); pk.y = pkbf(o[2], o[3]);
  pk.z = pkbf(o[4], o[5]); pk.w = pkbf(o[6], o[7]);
  *(uint4*)(par + (size_t)row * Ec + c) = pk;
}

// ---------------- GEMM1: 128x128 2-phase, A+B LDS dbuf (proven r0 structure)
// + conflict-free swizzle pair (row>>1)&3 (verified 0 conflicts in r2)
// + bijective XCD block swizzle (verified FETCH 70->39MB in r2) ----------------
__global__ __launch_bounds__(256) void k_gemm_uvqk(const unsigned short* __restrict__ A,
                                                   const unsigned short* __restrict__ BT,
                                                   const float* __restrict__ bias,
                                                   unsigned short* __restrict__ u_out,
                                                   unsigned short* __restrict__ vT,
                                                   unsigned short* __restrict__ qb,
                                                   unsigned short* __restrict__ kb){
  __shared__ __align__(16) unsigned short As[2][128 * 32];
  __shared__ __align__(16) unsigned short Bs[2][128 * 32];
  int tid = threadIdx.x;
  int lane = tid & 63, w = tid >> 6;
  int lm = lane & 15, quad = lane >> 4;
  int wm = w & 1, wn = w >> 1;
  int bid = blockIdx.y * gridDim.x + blockIdx.x;       // hw linear id (x fastest)
  int id2 = (bid & 7) * 256 + (bid >> 3);              // bijective XCD swizzle, nwg=2048
  int n0 = (id2 & 15) << 7, m0 = (id2 >> 4) << 7;
  int cat = n0 >> 9;
  bool swp = (cat != 1);
  int xc = quad ^ ((lm >> 1) & 3);                     // conflict-free read chunk

  int r0s = tid >> 2, c0s = ((tid & 3) ^ ((r0s >> 1) & 3)) * 16;
  int r1s = r0s + 64;                                  // (r1s>>1)&3 == (r0s>>1)&3
  const char* saA0 = (const char*)(A  + (size_t)(m0 + r0s) * Ec) + c0s;
  const char* saA1 = (const char*)(A  + (size_t)(m0 + r1s) * Ec) + c0s;
  const char* saB0 = (const char*)(BT + (size_t)(n0 + r0s) * Ec) + c0s;
  const char* saB1 = (const char*)(BT + (size_t)(n0 + r1s) * Ec) + c0s;

  gl_lds16(saA0, (char*)As[0] + tid * 16);
  gl_lds16(saA1, (char*)As[0] + tid * 16 + 4096);
  gl_lds16(saB0, (char*)Bs[0] + tid * 16);
  gl_lds16(saB1, (char*)Bs[0] + tid * 16 + 4096);
  __syncthreads();

  f32x4 acc[4][4] = {};
  #pragma unroll 1
  for (int kt = 0; kt < 16; ++kt){
    int cur = kt & 1, nb = cur ^ 1;
    if (kt < 15){
      int k0 = (kt + 1) * 64;   // bytes
      gl_lds16(saA0 + k0, (char*)As[nb] + tid * 16);
      gl_lds16(saA1 + k0, (char*)As[nb] + tid * 16 + 4096);
      gl_lds16(saB0 + k0, (char*)Bs[nb] + tid * 16);
      gl_lds16(saB1 + k0, (char*)Bs[nb] + tid * 16 + 4096);
    }
    bf16x8 af[4], bfr[4];
    #pragma unroll
    for (int s = 0; s < 4; ++s)
      af[s]  = ldb8(As[cur] + ((wm * 64 + s * 16 + lm) * 4 + xc) * 8);
    #pragma unroll
    for (int t = 0; t < 4; ++t)
      bfr[t] = ldb8(Bs[cur] + ((wn * 64 + t * 16 + lm) * 4 + xc) * 8);
    if (swp){
      #pragma unroll
      for (int s = 0; s < 4; ++s)
        #pragma unroll
        for (int t = 0; t < 4; ++t)
          acc[s][t] = mfma16(bfr[t], af[s], acc[s][t]);
    } else {
      #pragma unroll
      for (int s = 0; s < 4; ++s)
        #pragma unroll
        for (int t = 0; t < 4; ++t)
          acc[s][t] = mfma16(af[s], bfr[t], acc[s][t]);
    }
    __syncthreads();
  }

  if (cat == 1){
    #pragma unroll
    for (int t = 0; t < 4; ++t){
      int colg = n0 + wn * 64 + t * 16 + lm;
      float bv = bias[colg];
      int c = colg & 511, h = c >> 6, d = c & 63;
      #pragma unroll
      for (int s = 0; s < 4; ++s){
        int row = m0 + wm * 64 + s * 16 + quad * 4;
        int bb_ = row >> 11, sr = row & (Sc - 1);
        s4v pv = pk4(silu_f(acc[s][t][0] + bv), silu_f(acc[s][t][1] + bv),
                     silu_f(acc[s][t][2] + bv), silu_f(acc[s][t][3] + bv));
        *(s4v*)(vT + ((size_t)(bb_ * Hc + h) * Dc + d) * Sc + sr) = pv;
      }
    }
  } else {
    #pragma unroll
    for (int s = 0; s < 4; ++s){
      int row = m0 + wm * 64 + s * 16 + lm;
      int bb_ = row >> 11, sr = row & (Sc - 1);
      #pragma unroll
      for (int t = 0; t < 4; ++t){
        int colg = n0 + wn * 64 + t * 16 + quad * 4;
        float4 bv = *(const float4*)(bias + colg);
        float v0 = silu_f(acc[s][t][0] + bv.x);
        float v1 = silu_f(acc[s][t][1] + bv.y);
        float v2 = silu_f(acc[s][t][2] + bv.z);
        float v3 = silu_f(acc[s][t][3] + bv.w);
        int c = colg & 511, h = c >> 6, d = c & 63;
        if (cat == 0){
          *(s4v*)(u_out + (size_t)row * Ec + c) = pk4(v0, v1, v2, v3);
        } else if (cat == 2){
          *(s4v*)(qb + ((size_t)(bb_ * Hc + h) * Sc + sr) * Dc + d) =
            pk4(v0 * 0.125f, v1 * 0.125f, v2 * 0.125f, v3 * 0.125f);
        } else {
          *(s4v*)(kb + ((size_t)(bb_ * Hc + h) * Sc + sr) * Dc + d) = pk4(v0, v1, v2, v3);
        }
      }
    }
  }
}

// ---------------- HSTU silu attention: swizzled DMA K/V tiles, double-buffered
// + XCD grid swizzle: 8 contiguous bh per XCD (K/V 4MB/XCD = L2-resident) ----------------
__global__ __launch_bounds__(256) void k_attn(const unsigned short* __restrict__ qb,
                                              const unsigned short* __restrict__ kb,
                                              const unsigned short* __restrict__ vT,
                                              unsigned short* __restrict__ att){
  __shared__ __align__(16) unsigned short Kb[2][64 * 64];
  __shared__ __align__(16) unsigned short Vb[2][64 * 64];
  int tid = threadIdx.x;
  int lane = tid & 63, w = tid >> 6;
  int lm = lane & 15, quad = lane >> 4;
  int lmx = lm & 7;
  int bid = blockIdx.y * gridDim.x + blockIdx.x;   // nwg = 2048 (64 bh x 32 qblk)
  int id2 = (bid & 7) * 256 + (bid >> 3);          // XCD swizzle: XCD owns 8 bh x 32 qblk
  int bh = id2 >> 5;
  int qblk = 31 - (id2 & 31);                      // heavy blocks first (tail balance)
  int qrow = qblk * 64 + w * 16;
  int lastT = qblk;
  int ntiles = lastT + 1;

  const unsigned short* kbp = kb + (size_t)bh * Sc * Dc;
  const unsigned short* vbp = vT + (size_t)bh * Dc * Sc;
  const unsigned short* qp = qb + ((size_t)bh * Sc + qrow + lm) * Dc + quad * 8;
  bf16x8 qa0 = ldb8(qp), qa1 = ldb8(qp + 32);

  int r0s = tid >> 3, c0s = ((tid & 7) ^ (r0s & 7)) * 16;
  int r1s = (tid + 256) >> 3, c1s = (((tid + 256) & 7) ^ (r1s & 7)) * 16;
  const char* kS0 = (const char*)kbp + (size_t)r0s * 128 + c0s;
  const char* kS1 = (const char*)kbp + (size_t)r1s * 128 + c1s;
  const char* vS0 = (const char*)vbp + (size_t)r0s * (Sc * 2) + c0s;
  const char* vS1 = (const char*)vbp + (size_t)r1s * (Sc * 2) + c1s;

  { // prologue: stage tile 0
    gl_lds16(kS0, (char*)Kb[0] + tid * 16);
    gl_lds16(kS1, (char*)Kb[0] + tid * 16 + 4096);
    gl_lds16(vS0, (char*)Vb[0] + tid * 16);
    gl_lds16(vS1, (char*)Vb[0] + tid * 16 + 4096);
  }
  __syncthreads();

  f32x4 o[4] = {};
  int qg = qrow + lm;
  for (int kt = 0; kt < ntiles; ++kt){
    int cur = kt & 1, nb = cur ^ 1;
    if (kt + 1 < ntiles){
      int knb = (kt + 1) * 128;   // key offset in bytes
      gl_lds16(kS0 + (size_t)(kt + 1) * 8192, (char*)Kb[nb] + tid * 16);
      gl_lds16(kS1 + (size_t)(kt + 1) * 8192, (char*)Kb[nb] + tid * 16 + 4096);
      gl_lds16(vS0 + knb, (char*)Vb[nb] + tid * 16);
      gl_lds16(vS1 + knb, (char*)Vb[nb] + tid * 16 + 4096);
    }
    const unsigned short* Kc = Kb[cur];
    const unsigned short* Vc = Vb[cur];
    bool maskT = (kt == lastT);
    int key0 = kt * 64;
    #pragma unroll
    for (int s = 0; s < 4; ++s){
      int krow = (s * 16 + lm) * 8;
      bf16x8 kf0 = ldb8(Kc + (krow + (quad ^ lmx)) * 8);
      bf16x8 kf1 = ldb8(Kc + (krow + ((quad + 4) ^ lmx)) * 8);
      f32x4 sc = {0.f, 0.f, 0.f, 0.f};
      sc = mfma16(kf0, qa0, sc);
      sc = mfma16(kf1, qa1, sc);
      s4v pf;
      if (maskT){
        float m[4];
        #pragma unroll
        for (int r = 0; r < 4; ++r){
          int kg = key0 + s * 16 + quad * 4 + r;
          bool ok = (kg <= qg) && ((kg < HISTc) || (kg == qg));
          m[r] = ok ? silu_f(sc[r]) : 0.f;
        }
        pf = pk4(m[0], m[1], m[2], m[3]);
      } else {
        pf = pk4(silu_f(sc[0]), silu_f(sc[1]), silu_f(sc[2]), silu_f(sc[3]));
      }
      #pragma unroll
      for (int t = 0; t < 4; ++t){
        int vrow = (t * 16 + lm) * 8;
        s4v vf = *(const s4v*)(Vc + (vrow + ((2 * s + (quad >> 1)) ^ lmx)) * 8 + (quad & 1) * 4);
        o[t] = __builtin_amdgcn_mfma_f32_16x16x16bf16_1k(pf, vf, o[t], 0, 0, 0);
      }
    }
    __syncthreads();
  }
  int bb_ = bh >> 3, hh = bh & 7;
  #pragma unroll
  for (int t = 0; t < 4; ++t){
    int d = t * 16 + lm;
    unsigned int p01 = pkbf(o[t][0] * (1.f / Sc), o[t][1] * (1.f / Sc));
    unsigned int p23 = pkbf(o[t][2] * (1.f / Sc), o[t][3] * (1.f / Sc));
    size_t base = ((size_t)(bb_ * Sc + qrow + quad * 4) * Hc + hh) * Dc + d;
    att[base]               = (unsigned short)p01;
    att[base + Hc * Dc]     = (unsigned short)(p01 >> 16);
    att[base + 2 * Hc * Dc] = (unsigned short)p23;
    att[base + 3 * Hc * Dc] = (unsigned short)(p23 >> 16);
  }
}

// ---------------- GEMM2: out = par @ w_proj + x (A+B LDS dbuf, swizzled, C^T epilogue) ----------------
__global__ __launch_bounds__(256) void k_gemm_proj(const unsigned short* __restrict__ A,
                                                   const unsigned short* __restrict__ BT,
                                                   const float* __restrict__ x,
                                                   float* __restrict__ out){
  __shared__ __align__(16) unsigned short As[2][128 * 32];
  __shared__ __align__(16) unsigned short Bs[2][128 * 32];
  int tid = threadIdx.x;
  int lane = tid & 63, w = tid >> 6;
  int lm = lane & 15, quad = lane >> 4;
  int wm = w & 1, wn = w >> 1;
  int bid = blockIdx.y * gridDim.x + blockIdx.x;       // nwg = 512
  int id2 = (bid & 7) * 64 + (bid >> 3);               // bijective XCD swizzle
  int n0 = (id2 & 3) << 7, m0 = (id2 >> 2) << 7;
  int xc = quad ^ ((lm >> 1) & 3);

  int r0s = tid >> 2, c0s = ((tid & 3) ^ ((r0s >> 1) & 3)) * 16;
  int r1s = r0s + 64;
  const char* saA0 = (const char*)(A  + (size_t)(m0 + r0s) * Ec) + c0s;
  const char* saA1 = (const char*)(A  + (size_t)(m0 + r1s) * Ec) + c0s;
  const char* saB0 = (const char*)(BT + (size_t)(n0 + r0s) * Ec) + c0s;
  const char* saB1 = (const char*)(BT + (size_t)(n0 + r1s) * Ec) + c0s;

  gl_lds16(saA0, (char*)As[0] + tid * 16);
  gl_lds16(saA1, (char*)As[0] + tid * 16 + 4096);
  gl_lds16(saB0, (char*)Bs[0] + tid * 16);
  gl_lds16(saB1, (char*)Bs[0] + tid * 16 + 4096);
  __syncthreads();

  f32x4 acc[4][4] = {};
  #pragma unroll 1
  for (int kt = 0; kt < 16; ++kt){
    int cur = kt & 1, nb = cur ^ 1;
    if (kt < 15){
      int k0 = (kt + 1) * 64;   // bytes
      gl_lds16(saA0 + k0, (char*)As[nb] + tid * 16);
      gl_lds16(saA1 + k0, (char*)As[nb] + tid * 16 + 4096);
      gl_lds16(saB0 + k0, (char*)Bs[nb] + tid * 16);
      gl_lds16(saB1 + k0, (char*)Bs[nb] + tid * 16 + 4096);
    }
    bf16x8 af[4], bfr[4];
    #pragma unroll
    for (int s = 0; s < 4; ++s)
      af[s]  = ldb8(As[cur] + ((wm * 64 + s * 16 + lm) * 4 + xc) * 8);
    #pragma unroll
    for (int t = 0; t < 4; ++t)
      bfr[t] = ldb8(Bs[cur] + ((wn * 64 + t * 16 + lm) * 4 + xc) * 8);
    #pragma unroll
    for (int s = 0; s < 4; ++s)
      #pragma unroll
      for (int t = 0; t < 4; ++t)
        acc[s][t] = mfma16(bfr[t], af[s], acc[s][t]);   // C^T orientation
    __syncthreads();
  }

  #pragma unroll
  for (int s = 0; s < 4; ++s){
    int row = m0 + wm * 64 + s * 16 + lm;
    #pragma unroll
    for (int t = 0; t < 4; ++t){
      int col = n0 + wn * 64 + t * 16 + quad * 4;
      float4 xr = *(const float4*)(x + (size_t)row * Ec + col);
      float4 o4 = {acc[s][t][0] + xr.x, acc[s][t][1] + xr.y,
                   acc[s][t][2] + xr.z, acc[s][t][3] + xr.w};
      *(float4*)(out + (size_t)row * Ec + col) = o4;
    }
  }
}

extern "C" void kernel_launch(void* const* d_in, const int* in_sizes, int n_in,
                              void* d_out, int out_size, void* d_ws, size_t ws_size,
                              hipStream_t stream){
  (void)in_sizes; (void)n_in; (void)out_size; (void)ws_size;
  const float* x        = (const float*)d_in[0];
  const float* w_uvqk   = (const float*)d_in[1];
  const float* b_uvqk   = (const float*)d_in[2];
  const float* ln_in_w  = (const float*)d_in[3];
  const float* ln_in_b  = (const float*)d_in[4];
  const float* ln_out_w = (const float*)d_in[5];
  const float* ln_out_b = (const float*)d_in[6];
  const float* w_proj   = (const float*)d_in[7];
  float* out = (float*)d_out;

  char* ws = (char*)d_ws;
  unsigned short* xn  = (unsigned short*)(ws + 0);          // 16 MB, reused as `par` later
  unsigned short* wuT = (unsigned short*)(ws + 16777216);   // 2 MB
  unsigned short* wpT = (unsigned short*)(ws + 18874368);   // 0.5 MB
  unsigned short* ub  = (unsigned short*)(ws + 19398656);   // 16 MB (bf16)
  unsigned short* qbf = (unsigned short*)(ws + 52953088);   // 16 MB
  unsigned short* kbf = (unsigned short*)(ws + 69730304);   // 16 MB
  unsigned short* vTt = (unsigned short*)(ws + 86507520);   // 16 MB
  unsigned short* att = (unsigned short*)(ws + 103284736);  // 16 MB (bf16)

  dim3 tb(32, 32);
  k_transpose_cast<<<dim3(N1c / 32, Ec / 32), tb, 0, stream>>>(w_uvqk, wuT, Ec, N1c);
  k_transpose_cast<<<dim3(Ec / 32, Ec / 32), tb, 0, stream>>>(w_proj, wpT, Ec, Ec);
  k_ln_in<<<Tc / 4, 256, 0, stream>>>(x, ln_in_w, ln_in_b, xn);
  k_gemm_uvqk<<<dim3(N1c / 128, Tc / 128), 256, 0, stream>>>(xn, wuT, b_uvqk, ub, vTt, qbf, kbf);
  k_attn<<<dim3(Bc * Hc, Sc / 64), 256, 0, stream>>>(qbf, kbf, vTt, att);
  k_ln_mul<<<Tc / 4, 256, 0, stream>>>(att, ln_out_w, ln_out_b, ub, xn);
  k_gemm_proj<<<dim3(Ec / 128, Tc / 128), 256, 0, stream>>>(xn, wpT, x, out);
}

// Round 4
// 285.865 us; speedup vs baseline: 1.1176x; 1.0266x over previous
//
#include <hip/hip_runtime.h>
#include <hip/hip_bf16.h>

#define Bc 8
#define Sc 2048
#define Hc 8
#define Dc 64
#define Ec 512
#define NTc 64
#define Tc (Bc*Sc)
#define N1c (4*Hc*Dc)
#define HISTc (Sc - NTc)

typedef float f32x4 __attribute__((ext_vector_type(4)));
typedef __bf16 bf16x8 __attribute__((ext_vector_type(8)));
typedef short short8 __attribute__((ext_vector_type(8)));
typedef short s4v __attribute__((ext_vector_type(4)));

__device__ __forceinline__ unsigned short f2bf(float f){
  unsigned int u = __float_as_uint(f);
  u += 0x7fffu + ((u >> 16) & 1u);
  return (unsigned short)(u >> 16);
}
__device__ __forceinline__ float bf2f(unsigned short h){
  return __uint_as_float(((unsigned int)h) << 16);
}
// packed f32x2 -> bf16x2 (v_cvt_pk_bf16_f32)
__device__ __forceinline__ unsigned int pkbf(float a, float b){
  float2 f; f.x = a; f.y = b;
  __hip_bfloat162 h = __float22bfloat162_rn(f);
  unsigned int u;
  __builtin_memcpy(&u, &h, 4);
  return u;
}
__device__ __forceinline__ s4v pk4(float a, float b, float c, float d){
  uint2 u; u.x = pkbf(a, b); u.y = pkbf(c, d);
  return __builtin_bit_cast(s4v, u);
}
__device__ __forceinline__ float silu_f(float x){
  return x * __builtin_amdgcn_rcpf(1.f + __expf(-x));
}
__device__ __forceinline__ bf16x8 ldb8(const unsigned short* p){
  return __builtin_bit_cast(bf16x8, *(const short8*)p);
}
__device__ __forceinline__ f32x4 mfma16(bf16x8 a, bf16x8 b, f32x4 c){
  return __builtin_amdgcn_mfma_f32_16x16x32_bf16(a, b, c, 0, 0, 0);
}
__device__ __forceinline__ void gl_lds16(const void* g, void* l){
  __builtin_amdgcn_global_load_lds((const __attribute__((address_space(1))) unsigned int*)g,
                                   (__attribute__((address_space(3))) unsigned int*)l, 16, 0, 0);
}
// gfx950 16-lane-group swap: a[q1]<->b[q0], a[q3]<->b[q2] (both modified in place)
__device__ __forceinline__ void pswap16(unsigned int &a, unsigned int &b){
  asm volatile("v_permlane16_swap_b32 %0, %1" : "+v"(a), "+v"(b));
}

// ---------------- transpose + cast fp32 -> bf16 : out[c][r] = in[r][c] ----------------
__global__ __launch_bounds__(1024) void k_transpose_cast(const float* __restrict__ in,
                                                         unsigned short* __restrict__ out,
                                                         int R, int C){
  __shared__ float tile[32][33];
  int tx = threadIdx.x, ty = threadIdx.y;
  int c0 = blockIdx.x * 32, r0 = blockIdx.y * 32;
  tile[ty][tx] = in[(size_t)(r0 + ty) * C + c0 + tx];
  __syncthreads();
  out[(size_t)(c0 + ty) * R + r0 + tx] = f2bf(tile[tx][ty]);
}

// ---------------- input layernorm -> bf16 (one wave per row of 512) ----------------
__global__ __launch_bounds__(256) void k_ln_in(const float* __restrict__ x, const float* __restrict__ g,
                                               const float* __restrict__ b, unsigned short* __restrict__ xn){
  int lane = threadIdx.x & 63;
  int row = blockIdx.x * 4 + (threadIdx.x >> 6);
  const float* xr = x + (size_t)row * Ec + lane * 8;
  float4 v0 = *(const float4*)xr;
  float4 v1 = *(const float4*)(xr + 4);
  float vv[8] = {v0.x, v0.y, v0.z, v0.w, v1.x, v1.y, v1.z, v1.w};
  float s = 0.f, ss = 0.f;
  #pragma unroll
  for (int j = 0; j < 8; ++j){ s += vv[j]; ss += vv[j] * vv[j]; }
  #pragma unroll
  for (int m = 1; m < 64; m <<= 1){ s += __shfl_xor(s, m); ss += __shfl_xor(ss, m); }
  float mu = s * (1.f / Ec);
  float rs = rsqrtf(ss * (1.f / Ec) - mu * mu + 1e-5f);
  int c = lane * 8;
  float o[8];
  #pragma unroll
  for (int j = 0; j < 8; ++j) o[j] = (vv[j] - mu) * rs * g[c + j] + b[c + j];
  uint4 pk; pk.x = pkbf(o[0], o[1]); pk.y = pkbf(o[2], o[3]);
  pk.z = pkbf(o[4], o[5]); pk.w = pkbf(o[6], o[7]);
  *(uint4*)(xn + (size_t)row * Ec + c) = pk;
}

// ---------------- ln(attn_out) * u -> bf16 (att and u are bf16) ----------------
__global__ __launch_bounds__(256) void k_ln_mul(const unsigned short* __restrict__ att, const float* __restrict__ g,
                                                const float* __restrict__ b, const unsigned short* __restrict__ u,
                                                unsigned short* __restrict__ par){
  int lane = threadIdx.x & 63;
  int row = blockIdx.x * 4 + (threadIdx.x >> 6);
  short8 a8 = *(const short8*)(att + (size_t)row * Ec + lane * 8);
  short8 u8 = *(const short8*)(u + (size_t)row * Ec + lane * 8);
  float vv[8];
  #pragma unroll
  for (int j = 0; j < 8; ++j) vv[j] = bf2f((unsigned short)a8[j]);
  float s = 0.f, ss = 0.f;
  #pragma unroll
  for (int j = 0; j < 8; ++j){ s += vv[j]; ss += vv[j] * vv[j]; }
  #pragma unroll
  for (int m = 1; m < 64; m <<= 1){ s += __shfl_xor(s, m); ss += __shfl_xor(ss, m); }
  float mu = s * (1.f / Ec);
  float rs = rsqrtf(ss * (1.f / Ec) - mu * mu + 1e-5f);
  int c = lane * 8;
  float o[8];
  #pragma unroll
  for (int j = 0; j < 8; ++j){
    float uu = bf2f((unsigned short)u8[j]);
    o[j] = uu * ((vv[j] - mu) * rs * g[c + j] + b[c + j]);
  }
  uint4 pk; pk.x = pkbf(o[0], o[1]); pk.y = pkbf(o[2], o[3]);
  pk.z = pkbf(o[4], o[5]); pk.w = pkbf(o[6], o[7]);
  *(uint4*)(par + (size_t)row * Ec + c) = pk;
}

// ---------------- GEMM1: 128x128 2-phase, A+B LDS dbuf, conflict-free swizzle, XCD swizzle ----------------
__global__ __launch_bounds__(256) void k_gemm_uvqk(const unsigned short* __restrict__ A,
                                                   const unsigned short* __restrict__ BT,
                                                   const float* __restrict__ bias,
                                                   unsigned short* __restrict__ u_out,
                                                   unsigned short* __restrict__ vT,
                                                   unsigned short* __restrict__ qb,
                                                   unsigned short* __restrict__ kb){
  __shared__ __align__(16) unsigned short As[2][128 * 32];
  __shared__ __align__(16) unsigned short Bs[2][128 * 32];
  int tid = threadIdx.x;
  int lane = tid & 63, w = tid >> 6;
  int lm = lane & 15, quad = lane >> 4;
  int wm = w & 1, wn = w >> 1;
  int bid = blockIdx.y * gridDim.x + blockIdx.x;       // hw linear id (x fastest)
  int id2 = (bid & 7) * 256 + (bid >> 3);              // bijective XCD swizzle, nwg=2048
  int n0 = (id2 & 15) << 7, m0 = (id2 >> 4) << 7;
  int cat = n0 >> 9;
  bool swp = (cat != 1);
  int xc = quad ^ ((lm >> 1) & 3);                     // conflict-free read chunk

  int r0s = tid >> 2, c0s = ((tid & 3) ^ ((r0s >> 1) & 3)) * 16;
  int r1s = r0s + 64;                                  // (r1s>>1)&3 == (r0s>>1)&3
  const char* saA0 = (const char*)(A  + (size_t)(m0 + r0s) * Ec) + c0s;
  const char* saA1 = (const char*)(A  + (size_t)(m0 + r1s) * Ec) + c0s;
  const char* saB0 = (const char*)(BT + (size_t)(n0 + r0s) * Ec) + c0s;
  const char* saB1 = (const char*)(BT + (size_t)(n0 + r1s) * Ec) + c0s;

  gl_lds16(saA0, (char*)As[0] + tid * 16);
  gl_lds16(saA1, (char*)As[0] + tid * 16 + 4096);
  gl_lds16(saB0, (char*)Bs[0] + tid * 16);
  gl_lds16(saB1, (char*)Bs[0] + tid * 16 + 4096);
  __syncthreads();

  f32x4 acc[4][4] = {};
  #pragma unroll 1
  for (int kt = 0; kt < 16; ++kt){
    int cur = kt & 1, nb = cur ^ 1;
    if (kt < 15){
      int k0 = (kt + 1) * 64;   // bytes
      gl_lds16(saA0 + k0, (char*)As[nb] + tid * 16);
      gl_lds16(saA1 + k0, (char*)As[nb] + tid * 16 + 4096);
      gl_lds16(saB0 + k0, (char*)Bs[nb] + tid * 16);
      gl_lds16(saB1 + k0, (char*)Bs[nb] + tid * 16 + 4096);
    }
    bf16x8 af[4], bfr[4];
    #pragma unroll
    for (int s = 0; s < 4; ++s)
      af[s]  = ldb8(As[cur] + ((wm * 64 + s * 16 + lm) * 4 + xc) * 8);
    #pragma unroll
    for (int t = 0; t < 4; ++t)
      bfr[t] = ldb8(Bs[cur] + ((wn * 64 + t * 16 + lm) * 4 + xc) * 8);
    if (swp){
      #pragma unroll
      for (int s = 0; s < 4; ++s)
        #pragma unroll
        for (int t = 0; t < 4; ++t)
          acc[s][t] = mfma16(bfr[t], af[s], acc[s][t]);
    } else {
      #pragma unroll
      for (int s = 0; s < 4; ++s)
        #pragma unroll
        for (int t = 0; t < 4; ++t)
          acc[s][t] = mfma16(af[s], bfr[t], acc[s][t]);
    }
    __syncthreads();
  }

  if (cat == 1){
    #pragma unroll
    for (int t = 0; t < 4; ++t){
      int colg = n0 + wn * 64 + t * 16 + lm;
      float bv = bias[colg];
      int c = colg & 511, h = c >> 6, d = c & 63;
      #pragma unroll
      for (int s = 0; s < 4; ++s){
        int row = m0 + wm * 64 + s * 16 + quad * 4;
        int bb_ = row >> 11, sr = row & (Sc - 1);
        s4v pv = pk4(silu_f(acc[s][t][0] + bv), silu_f(acc[s][t][1] + bv),
                     silu_f(acc[s][t][2] + bv), silu_f(acc[s][t][3] + bv));
        *(s4v*)(vT + ((size_t)(bb_ * Hc + h) * Dc + d) * Sc + sr) = pv;
      }
    }
  } else {
    #pragma unroll
    for (int s = 0; s < 4; ++s){
      int row = m0 + wm * 64 + s * 16 + lm;
      int bb_ = row >> 11, sr = row & (Sc - 1);
      #pragma unroll
      for (int t = 0; t < 4; ++t){
        int colg = n0 + wn * 64 + t * 16 + quad * 4;
        float4 bv = *(const float4*)(bias + colg);
        float v0 = silu_f(acc[s][t][0] + bv.x);
        float v1 = silu_f(acc[s][t][1] + bv.y);
        float v2 = silu_f(acc[s][t][2] + bv.z);
        float v3 = silu_f(acc[s][t][3] + bv.w);
        int c = colg & 511, h = c >> 6, d = c & 63;
        if (cat == 0){
          *(s4v*)(u_out + (size_t)row * Ec + c) = pk4(v0, v1, v2, v3);
        } else if (cat == 2){
          *(s4v*)(qb + ((size_t)(bb_ * Hc + h) * Sc + sr) * Dc + d) =
            pk4(v0 * 0.125f, v1 * 0.125f, v2 * 0.125f, v3 * 0.125f);
        } else {
          *(s4v*)(kb + ((size_t)(bb_ * Hc + h) * Sc + sr) * Dc + d) = pk4(v0, v1, v2, v3);
        }
      }
    }
  }
}

// ---------------- HSTU silu attention: K=32 PV via permlane16_swap, unroll-2, immediates ----------------
// P exchange: QK (swapped operands) leaves thread(lm,quad) with P[q=lm][key=16s+4quad+r].
// PV A-frag needs P[q=lm][key=32ks+8*g(quad)+j] with free key-permutation g={0,2,1,3} applied
// to BOTH P and V k-slots. Two v_permlane16_swap per s-pair realize it exactly:
//   swap(d0_s0,d0_s1) -> pa dwords {0,2};  swap(d1_s0,d1_s1) -> pa dwords {1,3}.
// V-frag reads become contiguous ds_read_b128 at slot (4ks+g)^lmx (same CF pattern as K).
__global__ __launch_bounds__(256) void k_attn(const unsigned short* __restrict__ qb,
                                              const unsigned short* __restrict__ kb,
                                              const unsigned short* __restrict__ vT,
                                              unsigned short* __restrict__ att){
  __shared__ __align__(16) unsigned short Kb[2][64 * 64];
  __shared__ __align__(16) unsigned short Vb[2][64 * 64];
  int tid = threadIdx.x;
  int lane = tid & 63, w = tid >> 6;
  int lm = lane & 15, quad = lane >> 4;
  int lmx = lm & 7;
  int bid = blockIdx.y * gridDim.x + blockIdx.x;   // nwg = 2048 (64 bh x 32 qblk)
  int id2 = (bid & 7) * 256 + (bid >> 3);          // XCD swizzle: XCD owns 8 bh x 32 qblk
  int bh = id2 >> 5;
  int qblk = 31 - (id2 & 31);                      // heavy blocks first (tail balance)
  int qrow = qblk * 64 + w * 16;
  int lastT = qblk;
  int ntiles = lastT + 1;

  const unsigned short* kbp = kb + (size_t)bh * Sc * Dc;
  const unsigned short* vbp = vT + (size_t)bh * Dc * Sc;
  const unsigned short* qp = qb + ((size_t)bh * Sc + qrow + lm) * Dc + quad * 8;
  bf16x8 qa0 = ldb8(qp), qa1 = ldb8(qp + 32);

  int r0s = tid >> 3, c0s = ((tid & 7) ^ (r0s & 7)) * 16;
  int r1s = (tid + 256) >> 3, c1s = (((tid + 256) & 7) ^ (r1s & 7)) * 16;
  const char* kS0 = (const char*)kbp + (size_t)r0s * 128 + c0s;
  const char* kS1 = (const char*)kbp + (size_t)r1s * 128 + c1s;
  const char* vS0 = (const char*)vbp + (size_t)r0s * (Sc * 2) + c0s;
  const char* vS1 = (const char*)vbp + (size_t)r1s * (Sc * 2) + c1s;

  { // prologue: stage tile 0
    gl_lds16(kS0, (char*)Kb[0] + tid * 16);
    gl_lds16(kS1, (char*)Kb[0] + tid * 16 + 4096);
    gl_lds16(vS0, (char*)Vb[0] + tid * 16);
    gl_lds16(vS1, (char*)Vb[0] + tid * 16 + 4096);
  }
  __syncthreads();

  f32x4 o[4] = {};
  int qg = qrow + lm;
  int g = ((quad & 1) << 1) | (quad >> 1);         // key-slot permutation
  // hoisted per-thread LDS read offsets (ushort units); s/t parts are imm offsets
  int koff0 = lm * 64 + (quad ^ lmx) * 8;
  int koff1 = lm * 64 + (((quad + 4)) ^ lmx) * 8;
  int voff0 = lm * 64 + ((g ^ lmx)) * 8;
  int voff1 = lm * 64 + (((g + 4) ^ lmx)) * 8;

  auto step = [&](const unsigned short* Kc, const unsigned short* Vc,
                  char* dK, char* dV, int kt, bool do_stage){
    if (do_stage){
      gl_lds16(kS0 + (size_t)(kt + 1) * 8192, dK);
      gl_lds16(kS1 + (size_t)(kt + 1) * 8192, dK + 4096);
      gl_lds16(vS0 + (size_t)(kt + 1) * 128, dV);
      gl_lds16(vS1 + (size_t)(kt + 1) * 128, dV + 4096);
    }
    bool maskT = (kt == lastT);
    int key0 = kt * 64;
    unsigned int dlo[4], dhi[4];
    #pragma unroll
    for (int s = 0; s < 4; ++s){
      bf16x8 kf0 = ldb8(Kc + koff0 + s * 1024);
      bf16x8 kf1 = ldb8(Kc + koff1 + s * 1024);
      f32x4 sc = {0.f, 0.f, 0.f, 0.f};
      sc = mfma16(kf0, qa0, sc);
      sc = mfma16(kf1, qa1, sc);
      float p[4];
      if (maskT){
        #pragma unroll
        for (int r = 0; r < 4; ++r){
          int kg = key0 + s * 16 + quad * 4 + r;
          bool ok = (kg <= qg) && ((kg < HISTc) || (kg == qg));
          p[r] = ok ? silu_f(sc[r]) : 0.f;
        }
      } else {
        #pragma unroll
        for (int r = 0; r < 4; ++r) p[r] = silu_f(sc[r]);
      }
      dlo[s] = pkbf(p[0], p[1]);
      dhi[s] = pkbf(p[2], p[3]);
    }
    pswap16(dlo[0], dlo[1]); pswap16(dhi[0], dhi[1]);
    pswap16(dlo[2], dlo[3]); pswap16(dhi[2], dhi[3]);
    uint4 pa0u, pa1u;
    pa0u.x = dlo[0]; pa0u.y = dhi[0]; pa0u.z = dlo[1]; pa0u.w = dhi[1];
    pa1u.x = dlo[2]; pa1u.y = dhi[2]; pa1u.z = dlo[3]; pa1u.w = dhi[3];
    bf16x8 pa0 = __builtin_bit_cast(bf16x8, pa0u);
    bf16x8 pa1 = __builtin_bit_cast(bf16x8, pa1u);
    __builtin_amdgcn_s_setprio(1);
    #pragma unroll
    for (int t = 0; t < 4; ++t){
      bf16x8 vf0 = ldb8(Vc + voff0 + t * 1024);
      bf16x8 vf1 = ldb8(Vc + voff1 + t * 1024);
      o[t] = mfma16(pa0, vf0, o[t]);
      o[t] = mfma16(pa1, vf1, o[t]);
    }
    __builtin_amdgcn_s_setprio(0);
    __syncthreads();
  };

  int kt = 0;
  #pragma unroll 1
  for (; kt + 2 <= ntiles; kt += 2){
    step(Kb[0], Vb[0], (char*)Kb[1] + tid * 16, (char*)Vb[1] + tid * 16, kt, true);
    step(Kb[1], Vb[1], (char*)Kb[0] + tid * 16, (char*)Vb[0] + tid * 16, kt + 1, kt + 2 < ntiles);
  }
  if (kt < ntiles)
    step(Kb[0], Vb[0], (char*)Kb[1] + tid * 16, (char*)Vb[1] + tid * 16, kt, false);

  int bb_ = bh >> 3, hh = bh & 7;
  #pragma unroll
  for (int t = 0; t < 4; ++t){
    int d = t * 16 + lm;
    unsigned int p01 = pkbf(o[t][0] * (1.f / Sc), o[t][1] * (1.f / Sc));
    unsigned int p23 = pkbf(o[t][2] * (1.f / Sc), o[t][3] * (1.f / Sc));
    size_t base = ((size_t)(bb_ * Sc + qrow + quad * 4) * Hc + hh) * Dc + d;
    att[base]               = (unsigned short)p01;
    att[base + Hc * Dc]     = (unsigned short)(p01 >> 16);
    att[base + 2 * Hc * Dc] = (unsigned short)p23;
    att[base + 3 * Hc * Dc] = (unsigned short)(p23 >> 16);
  }
}

// ---------------- GEMM2: out = par @ w_proj + x (A+B LDS dbuf, swizzled, C^T epilogue) ----------------
__global__ __launch_bounds__(256) void k_gemm_proj(const unsigned short* __restrict__ A,
                                                   const unsigned short* __restrict__ BT,
                                                   const float* __restrict__ x,
                                                   float* __restrict__ out){
  __shared__ __align__(16) unsigned short As[2][128 * 32];
  __shared__ __align__(16) unsigned short Bs[2][128 * 32];
  int tid = threadIdx.x;
  int lane = tid & 63, w = tid >> 6;
  int lm = lane & 15, quad = lane >> 4;
  int wm = w & 1, wn = w >> 1;
  int bid = blockIdx.y * gridDim.x + blockIdx.x;       // nwg = 512
  int id2 = (bid & 7) * 64 + (bid >> 3);               // bijective XCD swizzle
  int n0 = (id2 & 3) << 7, m0 = (id2 >> 2) << 7;
  int xc = quad ^ ((lm >> 1) & 3);

  int r0s = tid >> 2, c0s = ((tid & 3) ^ ((r0s >> 1) & 3)) * 16;
  int r1s = r0s + 64;
  const char* saA0 = (const char*)(A  + (size_t)(m0 + r0s) * Ec) + c0s;
  const char* saA1 = (const char*)(A  + (size_t)(m0 + r1s) * Ec) + c0s;
  const char* saB0 = (const char*)(BT + (size_t)(n0 + r0s) * Ec) + c0s;
  const char* saB1 = (const char*)(BT + (size_t)(n0 + r1s) * Ec) + c0s;

  gl_lds16(saA0, (char*)As[0] + tid * 16);
  gl_lds16(saA1, (char*)As[0] + tid * 16 + 4096);
  gl_lds16(saB0, (char*)Bs[0] + tid * 16);
  gl_lds16(saB1, (char*)Bs[0] + tid * 16 + 4096);
  __syncthreads();

  f32x4 acc[4][4] = {};
  #pragma unroll 1
  for (int kt = 0; kt < 16; ++kt){
    int cur = kt & 1, nb = cur ^ 1;
    if (kt < 15){
      int k0 = (kt + 1) * 64;   // bytes
      gl_lds16(saA0 + k0, (char*)As[nb] + tid * 16);
      gl_lds16(saA1 + k0, (char*)As[nb] + tid * 16 + 4096);
      gl_lds16(saB0 + k0, (char*)Bs[nb] + tid * 16);
      gl_lds16(saB1 + k0, (char*)Bs[nb] + tid * 16 + 4096);
    }
    bf16x8 af[4], bfr[4];
    #pragma unroll
    for (int s = 0; s < 4; ++s)
      af[s]  = ldb8(As[cur] + ((wm * 64 + s * 16 + lm) * 4 + xc) * 8);
    #pragma unroll
    for (int t = 0; t < 4; ++t)
      bfr[t] = ldb8(Bs[cur] + ((wn * 64 + t * 16 + lm) * 4 + xc) * 8);
    #pragma unroll
    for (int s = 0; s < 4; ++s)
      #pragma unroll
      for (int t = 0; t < 4; ++t)
        acc[s][t] = mfma16(bfr[t], af[s], acc[s][t]);   // C^T orientation
    __syncthreads();
  }

  #pragma unroll
  for (int s = 0; s < 4; ++s){
    int row = m0 + wm * 64 + s * 16 + lm;
    #pragma unroll
    for (int t = 0; t < 4; ++t){
      int col = n0 + wn * 64 + t * 16 + quad * 4;
      float4 xr = *(const float4*)(x + (size_t)row * Ec + col);
      float4 o4 = {acc[s][t][0] + xr.x, acc[s][t][1] + xr.y,
                   acc[s][t][2] + xr.z, acc[s][t][3] + xr.w};
      *(float4*)(out + (size_t)row * Ec + col) = o4;
    }
  }
}

extern "C" void kernel_launch(void* const* d_in, const int* in_sizes, int n_in,
                              void* d_out, int out_size, void* d_ws, size_t ws_size,
                              hipStream_t stream){
  (void)in_sizes; (void)n_in; (void)out_size; (void)ws_size;
  const float* x        = (const float*)d_in[0];
  const float* w_uvqk   = (const float*)d_in[1];
  const float* b_uvqk   = (const float*)d_in[2];
  const float* ln_in_w  = (const float*)d_in[3];
  const float* ln_in_b  = (const float*)d_in[4];
  const float* ln_out_w = (const float*)d_in[5];
  const float* ln_out_b = (const float*)d_in[6];
  const float* w_proj   = (const float*)d_in[7];
  float* out = (float*)d_out;

  char* ws = (char*)d_ws;
  unsigned short* xn  = (unsigned short*)(ws + 0);          // 16 MB, reused as `par` later
  unsigned short* wuT = (unsigned short*)(ws + 16777216);   // 2 MB
  unsigned short* wpT = (unsigned short*)(ws + 18874368);   // 0.5 MB
  unsigned short* ub  = (unsigned short*)(ws + 19398656);   // 16 MB (bf16)
  unsigned short* qbf = (unsigned short*)(ws + 52953088);   // 16 MB
  unsigned short* kbf = (unsigned short*)(ws + 69730304);   // 16 MB
  unsigned short* vTt = (unsigned short*)(ws + 86507520);   // 16 MB
  unsigned short* att = (unsigned short*)(ws + 103284736);  // 16 MB (bf16)

  dim3 tb(32, 32);
  k_transpose_cast<<<dim3(N1c / 32, Ec / 32), tb, 0, stream>>>(w_uvqk, wuT, Ec, N1c);
  k_transpose_cast<<<dim3(Ec / 32, Ec / 32), tb, 0, stream>>>(w_proj, wpT, Ec, Ec);
  k_ln_in<<<Tc / 4, 256, 0, stream>>>(x, ln_in_w, ln_in_b, xn);
  k_gemm_uvqk<<<dim3(N1c / 128, Tc / 128), 256, 0, stream>>>(xn, wuT, b_uvqk, ub, vTt, qbf, kbf);
  k_attn<<<dim3(Bc * Hc, Sc / 64), 256, 0, stream>>>(qbf, kbf, vTt, att);
  k_ln_mul<<<Tc / 4, 256, 0, stream>>>(att, ln_out_w, ln_out_b, ub, xn);
  k_gemm_proj<<<dim3(Ec / 128, Tc / 128), 256, 0, stream>>>(xn, wpT, x, out);
}